// Round 5
// baseline (324.296 us; speedup 1.0000x reference)
//
#include <hip/hip_runtime.h>

#define SEQ 2048
#define DIM 1024
#define NH 16
#define HDIM 64
#define PFF 4096
#define NROWS 4096  // B*S
#define BATCH 2
#define NQKV 3072

typedef unsigned short u16;
typedef unsigned int u32;
typedef __attribute__((ext_vector_type(8))) short short8;
typedef __attribute__((ext_vector_type(4))) float f32x4;
typedef __attribute__((ext_vector_type(16))) float f32x16;

__device__ inline float b2f(u16 u){ return __uint_as_float(((u32)u)<<16); }
__device__ inline u16 f2b(float f){
  u32 u = __float_as_uint(f);
  u32 r = u + 0x7FFFu + ((u>>16)&1u);
  return (u16)(r>>16);
}

// C-style casts: clang allows addrspacecast via C-style cast (static_cast does not)
#define AS1C(p) ((const __attribute__((address_space(1))) unsigned int*)(p))
#define AS3P(p) ((__attribute__((address_space(3))) unsigned int*)(p))

// ---------------- elementwise cast fp32 -> bf16 (float4 per thread) ----------------
__global__ void k_cast_bf16(const float* __restrict__ in, u16* __restrict__ out, int n4){
  int i = blockIdx.x*256 + threadIdx.x;
  if (i >= n4) return;
  float4 v = ((const float4*)in)[i];
  ushort4 o;
  o.x = f2b(v.x); o.y = f2b(v.y); o.z = f2b(v.z); o.w = f2b(v.w);
  ((ushort4*)out)[i] = o;
}

// ---------------- transpose + cast: in fp32 [R][C] -> out bf16 [C][R] ----------------
__global__ __launch_bounds__(256) void k_transpose_cast(const float* __restrict__ in,
                                                        u16* __restrict__ out, int R, int C){
  __shared__ float tile[32][33];
  int tx = threadIdx.x & 31, ty = threadIdx.x >> 5;
  int c0 = blockIdx.x*32, r0 = blockIdx.y*32;
  #pragma unroll
  for (int i=0;i<4;++i)
    tile[ty+i*8][tx] = in[(size_t)(r0+ty+i*8)*C + c0 + tx];
  __syncthreads();
  #pragma unroll
  for (int i=0;i<4;++i)
    out[(size_t)(c0+ty+i*8)*R + r0 + tx] = f2b(tile[tx][ty+i*8]);
}

// ---------------- bf16 transpose: VT[d][r] = QKV[r][2048+d] ----------------
__global__ __launch_bounds__(256) void k_transpose_v(const u16* __restrict__ QKV, u16* __restrict__ VT){
  __shared__ u16 tile[32][34];
  int tx = threadIdx.x & 31, ty = threadIdx.x >> 5;
  int d0 = blockIdx.x*32, r0 = blockIdx.y*32;
  #pragma unroll
  for (int i=0;i<4;++i)
    tile[ty+i*8][tx] = QKV[(size_t)(r0+ty+i*8)*NQKV + 2048 + d0 + tx];
  __syncthreads();
  #pragma unroll
  for (int i=0;i<4;++i)
    VT[(size_t)(d0+ty+i*8)*NROWS + r0 + tx] = tile[tx][ty+i*8];
}

// ---------------- pack 3 bias vectors ----------------
__global__ void k_pack3(const float* __restrict__ a, const float* __restrict__ b,
                        const float* __restrict__ c, float* __restrict__ o){
  int i = blockIdx.x*256 + threadIdx.x;
  if (i >= NQKV) return;
  o[i] = i < 1024 ? a[i] : (i < 2048 ? b[i-1024] : c[i-2048]);
}

// ---------------- GEMM: C[M][N] = A[M][K](bf16) * Bt[N][K](bf16)^T (+ bias) ----------------
// 128x128 tile, BK=64, global_load_lds staging with pre-swizzled source (m173/m97).
// lda/ldb allow split-K offsets into wider matrices.
template<bool RELU, bool BF16OUT, bool BIAS>
__global__ __launch_bounds__(256) void k_gemm(
    const u16* __restrict__ A, const u16* __restrict__ Bt,
    const float* __restrict__ bias, void* __restrict__ Cp,
    int M, int N, int K, int lda, int ldb){
  __shared__ __align__(16) char lds[32768];
  const int tid = threadIdx.x;
  const int lane = tid & 63, wid = tid >> 6;
  const int quad = lane >> 4, l15 = lane & 15;
  const int wr = wid >> 1, wc = wid & 1;
  const int rowBase = blockIdx.y * 128, colBase = blockIdx.x * 128;
  f32x4 acc[4][4] = {};
  const int srow = lane >> 3;
  const int scol = lane & 7;
  for (int k0 = 0; k0 < K; k0 += 64) {
    __syncthreads();
    #pragma unroll
    for (int i=0;i<4;++i){
      int wch = wid*4 + i;                // wave-chunk 0..15 (8 rows each)
      int row = wch*8 + srow;             // 0..127
      int c   = scol ^ (row & 7);         // pre-swizzled source chunk
      const u16* ga = A  + (size_t)(rowBase+row)*lda + k0 + c*8;
      __builtin_amdgcn_global_load_lds(AS1C(ga), AS3P(lds + wch*1024), 16, 0, 0);
      const u16* gb = Bt + (size_t)(colBase+row)*ldb + k0 + c*8;
      __builtin_amdgcn_global_load_lds(AS1C(gb), AS3P(lds + 16384 + wch*1024), 16, 0, 0);
    }
    __syncthreads();
    #pragma unroll
    for (int kk=0;kk<2;++kk){
      short8 af[4], bfr[4];
      #pragma unroll
      for (int m=0;m<4;++m){
        int r = wr*64 + m*16 + l15;
        af[m] = *(const short8*)(lds + ((r*128 + kk*64 + quad*16) ^ ((r&7)<<4)));
      }
      #pragma unroll
      for (int n=0;n<4;++n){
        int r = wc*64 + n*16 + l15;
        bfr[n] = *(const short8*)(lds + 16384 + ((r*128 + kk*64 + quad*16) ^ ((r&7)<<4)));
      }
      #pragma unroll
      for (int m=0;m<4;++m)
        #pragma unroll
        for (int n=0;n<4;++n)
          acc[m][n] = __builtin_amdgcn_mfma_f32_16x16x32_bf16(af[m], bfr[n], acc[m][n], 0,0,0);
    }
  }
  #pragma unroll
  for (int m=0;m<4;++m){
    #pragma unroll
    for (int n=0;n<4;++n){
      int col = colBase + wc*64 + n*16 + l15;
      float bv = BIAS ? bias[col] : 0.f;
      #pragma unroll
      for (int j=0;j<4;++j){
        int row = rowBase + wr*64 + m*16 + quad*4 + j;
        float v = acc[m][n][j] + bv;
        if (RELU) v = fmaxf(v, 0.f);
        if (BF16OUT) ((u16*)Cp)[(size_t)row*N + col] = f2b(v);
        else         ((float*)Cp)[(size_t)row*N + col] = v;
      }
    }
  }
}

// ---------------- RoPE in-place on fused QKV: Q cols scaled by 1/8, K cols ----------------
__global__ void k_rope(u16* __restrict__ QKV,
                       const float* __restrict__ cosT, const float* __restrict__ sinT){
  int idx = blockIdx.x*256 + threadIdx.x;   // NROWS*512 threads, one (q,k) pair each
  int row = idx >> 9, p = idx & 511;
  int s = row & (SEQ-1);
  float c = cosT[s*512 + p], sn = sinT[s*512 + p];
  u16* qp = QKV + (size_t)row*NQKV + 2*p;
  u16* kp = qp + 1024;
  ushort2 q = *(ushort2*)qp;
  ushort2 k = *(ushort2*)kp;
  float qx = b2f(q.x), qy = b2f(q.y), kx = b2f(k.x), ky = b2f(k.y);
  const float scale = 0.125f;   // 1/sqrt(HD)
  ushort2 qo, ko;
  qo.x = f2b((qx*c - qy*sn)*scale);
  qo.y = f2b((qx*sn + qy*c)*scale);
  ko.x = f2b(kx*c - ky*sn);
  ko.y = f2b(kx*sn + ky*c);
  *(ushort2*)qp = qo;
  *(ushort2*)kp = ko;
}

// ---------------- flash attention v2: swapped QK^T, in-register softmax ----------------
// 4 warps x 32 q-rows (q-tile 128), KVBLK=64, mfma_32x32x16.
// Swapped QK^T: pacc[kb][r] = S[k=32kb+crow(r,hi)][q=lane&31], crow(r,hi)=(r&3)+8*(r>>2)+4*hi.
// Lane owns q-column lane&31 -> reduces in-register + one shfl_xor(32).
// P->PV A-frag via cvt_pk_bf16 + permlane32_swap (T12). Defer-max (T13).
// LDS: K[64][64] swz @0 (8KB) | Vt[64][64] swz @8192 (8KB)
__global__ __launch_bounds__(256) void k_attn(
    const u16* __restrict__ QKV, const u16* __restrict__ VT, u16* __restrict__ Xo){
  const int qt = blockIdx.x, h = blockIdx.y, b = blockIdx.z;
  const int tid = threadIdx.x, lane = tid & 63, wid = tid >> 6;
  const int l31 = lane & 31, hi = lane >> 5;
  __shared__ __align__(16) char lds[16384];
  const int srow = lane >> 3, scol = lane & 7;

  // Q -> registers: qf[dk] = Q[q=qt*128+wid*32+l31][d=dk*16+8*hi .. +7]
  short8 qf[4];
  {
    const u16* qrow = QKV + (size_t)(b*SEQ + qt*128 + wid*32 + l31)*NQKV + h*HDIM;
    #pragma unroll
    for (int dk=0; dk<4; ++dk)
      qf[dk] = *(const short8*)(qrow + dk*16 + 8*hi);
  }
  float m_run = -1e30f, s_run = 0.f;
  f32x16 oacc[2] = {};
  const size_t krow0 = (size_t)(b*SEQ);
  for (int kt=0; kt<SEQ/64; ++kt){
    __syncthreads();
    #pragma unroll
    for (int i=0;i<2;++i){
      int wch = wid*2 + i;           // 0..7 (8 rows each)
      int row = wch*8 + srow;
      int c = scol ^ (row & 7);
      const u16* gk = QKV + (krow0 + kt*64 + row)*NQKV + 1024 + h*HDIM + c*8;
      __builtin_amdgcn_global_load_lds(AS1C(gk), AS3P(lds + wch*1024), 16, 0, 0);
      const u16* gv = VT + (size_t)(h*HDIM + row)*NROWS + b*SEQ + kt*64 + c*8;
      __builtin_amdgcn_global_load_lds(AS1C(gv), AS3P(lds + 8192 + wch*1024), 16, 0, 0);
    }
    __syncthreads();
    // ---- S^T = K Q^T : pacc[kb][r] = S[32kb+crow(r,hi)][q=l31]
    f32x16 pacc[2] = {};
    #pragma unroll
    for (int kb=0;kb<2;++kb){
      #pragma unroll
      for (int dk=0;dk<4;++dk){
        int row = kb*32 + l31;
        short8 kf = *(const short8*)(lds + ((row*128 + dk*32 + 16*hi) ^ ((row&7)<<4)));
        pacc[kb] = __builtin_amdgcn_mfma_f32_32x32x16_bf16(kf, qf[dk], pacc[kb], 0,0,0);
      }
    }
    // ---- tile max for q=l31 (in-register + partner half)
    float tmax = -1e30f;
    #pragma unroll
    for (int kb=0;kb<2;++kb)
      #pragma unroll
      for (int r=0;r<16;++r) tmax = fmaxf(tmax, pacc[kb][r]);
    tmax = fmaxf(tmax, __shfl_xor(tmax, 32));
    // ---- defer-max (T13): rescale only when growth > 8
    if (__any(tmax > m_run + 8.0f)){
      float mnew = fmaxf(m_run, tmax);
      float a = __expf(m_run - mnew);
      s_run *= a;
      m_run = mnew;
      #pragma unroll
      for (int r=0;r<16;++r){
        int src = (r&3) + 8*(r>>2) + 4*hi;   // q-row of acc reg r
        float ar = __shfl(a, src);
        oacc[0][r] *= ar;
        oacc[1][r] *= ar;
      }
    }
    // ---- P = exp(S - m_run), row-sum
    float p[2][16];
    float psum = 0.f;
    #pragma unroll
    for (int kb=0;kb<2;++kb)
      #pragma unroll
      for (int r=0;r<16;++r){
        float e = __expf(pacc[kb][r] - m_run);
        p[kb][r] = e;
        psum += e;
      }
    psum += __shfl_xor(psum, 32);
    s_run += psum;
    // ---- pack P into PV A-fragments: pa[ks=2*kb+s]
    short8 pa[4];
    #pragma unroll
    for (int kb=0;kb<2;++kb){
      #pragma unroll
      for (int s=0;s<2;++s){
        u32 X0, X1, Y0, Y1;
        asm("v_cvt_pk_bf16_f32 %0, %1, %2" : "=v"(X0) : "v"(p[kb][8*s+0]), "v"(p[kb][8*s+1]));
        asm("v_cvt_pk_bf16_f32 %0, %1, %2" : "=v"(X1) : "v"(p[kb][8*s+2]), "v"(p[kb][8*s+3]));
        asm("v_cvt_pk_bf16_f32 %0, %1, %2" : "=v"(Y0) : "v"(p[kb][8*s+4]), "v"(p[kb][8*s+5]));
        asm("v_cvt_pk_bf16_f32 %0, %1, %2" : "=v"(Y1) : "v"(p[kb][8*s+6]), "v"(p[kb][8*s+7]));
        asm volatile("v_permlane32_swap_b32 %0, %1" : "+v"(X0), "+v"(Y0));
        asm volatile("v_permlane32_swap_b32 %0, %1" : "+v"(X1), "+v"(Y1));
        union { u32 w[4]; short8 s8; } pu;
        pu.w[0] = X0; pu.w[1] = X1; pu.w[2] = Y0; pu.w[3] = Y1;
        pa[2*kb+s] = pu.s8;
      }
    }
    // ---- O += P V   (B-frag from Vt[d][k] tile)
    #pragma unroll
    for (int db=0;db<2;++db){
      #pragma unroll
      for (int ks=0;ks<4;++ks){
        int row = db*32 + l31;
        short8 vf = *(const short8*)(lds + 8192 + ((row*128 + ks*32 + 16*hi) ^ ((row&7)<<4)));
        oacc[db] = __builtin_amdgcn_mfma_f32_32x32x16_bf16(pa[ks], vf, oacc[db], 0,0,0);
      }
    }
  }
  // ---- epilogue: divide by row-sum (redistribute s_run to acc rows), write out
  #pragma unroll
  for (int r=0;r<16;++r){
    int crow = (r&3) + 8*(r>>2) + 4*hi;
    float sq = __shfl(s_run, crow);
    float rs = __builtin_amdgcn_rcpf(sq);
    int grow = b*SEQ + qt*128 + wid*32 + crow;
    Xo[(size_t)grow*DIM + h*HDIM + l31]      = f2b(oacc[0][r] * rs);
    Xo[(size_t)grow*DIM + h*HDIM + 32 + l31] = f2b(oacc[1][r] * rs);
  }
}

// ---------------- residual + 2 partials + layernorm (row per block) ----------------
template<bool WBF>
__global__ __launch_bounds__(256) void k_ln3(
    const float* __restrict__ a, const float* __restrict__ b, const float* __restrict__ c,
    const float* __restrict__ g, const float* __restrict__ be,
    float* __restrict__ outf, u16* __restrict__ outb){
  const int row = blockIdx.x, tid = threadIdx.x;
  __shared__ float red[8];
  float4 av = ((const float4*)(a + (size_t)row*DIM))[tid];
  float4 bv = ((const float4*)(b + (size_t)row*DIM))[tid];
  float4 cv = ((const float4*)(c + (size_t)row*DIM))[tid];
  float x0 = av.x+bv.x+cv.x, x1 = av.y+bv.y+cv.y, x2 = av.z+bv.z+cv.z, x3 = av.w+bv.w+cv.w;
  float s = x0+x1+x2+x3;
  #pragma unroll
  for (int o=32;o>=1;o>>=1) s += __shfl_down(s, o);
  if ((tid&63)==0) red[tid>>6] = s;
  __syncthreads();
  float mean = (red[0]+red[1]+red[2]+red[3]) * (1.0f/DIM);
  float d0=x0-mean, d1=x1-mean, d2=x2-mean, d3=x3-mean;
  float vs = d0*d0+d1*d1+d2*d2+d3*d3;
  #pragma unroll
  for (int o=32;o>=1;o>>=1) vs += __shfl_down(vs, o);
  if ((tid&63)==0) red[4+(tid>>6)] = vs;
  __syncthreads();
  float var = (red[4]+red[5]+red[6]+red[7]) * (1.0f/DIM);
  float rs = rsqrtf(var + 1e-5f);
  float4 gv = ((const float4*)g)[tid];
  float4 bev = ((const float4*)be)[tid];
  float4 y;
  y.x = d0*rs*gv.x + bev.x;
  y.y = d1*rs*gv.y + bev.y;
  y.z = d2*rs*gv.z + bev.z;
  y.w = d3*rs*gv.w + bev.w;
  ((float4*)(outf + (size_t)row*DIM))[tid] = y;
  if (WBF){
    ushort4 o4; o4.x=f2b(y.x); o4.y=f2b(y.y); o4.z=f2b(y.z); o4.w=f2b(y.w);
    ((ushort4*)(outb + (size_t)row*DIM))[tid] = o4;
  }
}

extern "C" void kernel_launch(void* const* d_in, const int* in_sizes, int n_in,
                              void* d_out, int out_size, void* d_ws, size_t ws_size,
                              hipStream_t stream){
  (void)in_sizes; (void)n_in; (void)out_size; (void)ws_size;
  const float* src  = (const float*)d_in[0];
  const float* Wq   = (const float*)d_in[1];
  const float* bq   = (const float*)d_in[2];
  const float* Wk   = (const float*)d_in[3];
  const float* bk   = (const float*)d_in[4];
  const float* Wv   = (const float*)d_in[5];
  const float* bv   = (const float*)d_in[6];
  const float* Wo   = (const float*)d_in[7];
  const float* bo   = (const float*)d_in[8];
  const float* ln1g = (const float*)d_in[9];
  const float* ln1b = (const float*)d_in[10];
  const float* W1   = (const float*)d_in[11];
  const float* b1   = (const float*)d_in[12];
  const float* W2   = (const float*)d_in[13];
  const float* b2   = (const float*)d_in[14];
  const float* ln2g = (const float*)d_in[15];
  const float* ln2b = (const float*)d_in[16];
  const float* rc   = (const float*)d_in[17];
  const float* rsn  = (const float*)d_in[18];

  char* ws = (char*)d_ws;
  const size_t MB = (size_t)1<<20;
  // Region plan (peak ~129MB):
  //  0-8    Xbf (dead after QKV gemm)
  //  8-40   QKV(8-32)+VTb(32-40) during attn; then ao_a(8-24)/ao_b(24-40);
  //         then ff2_a(8-24)/ff2_b(24-40)
  //  40-48  xat | 48-56 hbf | 56-80 weights | 80-112 ff1 | 112-128 h | 128+ bqkv
  u16* Xbf   = (u16*)(ws);
  u16* QKV   = (u16*)(ws + 8*MB);
  u16* VTb   = (u16*)(ws + 32*MB);
  float* ao_a  = (float*)(ws + 8*MB);
  float* ao_b  = (float*)(ws + 24*MB);
  float* ff2_a = ao_a;
  float* ff2_b = ao_b;
  u16* xat   = (u16*)(ws + 40*MB);
  u16* hbf   = (u16*)(ws + 48*MB);
  u16* WqkvT = (u16*)(ws + 56*MB);
  u16* WoT   = (u16*)(ws + 62*MB);
  u16* W1T   = (u16*)(ws + 64*MB);
  u16* W2T   = (u16*)(ws + 72*MB);
  u16* ff1   = (u16*)(ws + 80*MB);
  float* h   = (float*)(ws + 112*MB);
  float* bqkv= (float*)(ws + 128*MB);

  dim3 blk(256);
  k_cast_bf16<<<dim3(NROWS*DIM/1024), blk, 0, stream>>>(src, Xbf, NROWS*DIM/4);
  k_transpose_cast<<<dim3(DIM/32, DIM/32), blk, 0, stream>>>(Wq, WqkvT, DIM, DIM);
  k_transpose_cast<<<dim3(DIM/32, DIM/32), blk, 0, stream>>>(Wk, WqkvT + (size_t)1024*1024, DIM, DIM);
  k_transpose_cast<<<dim3(DIM/32, DIM/32), blk, 0, stream>>>(Wv, WqkvT + (size_t)2048*1024, DIM, DIM);
  k_transpose_cast<<<dim3(DIM/32, DIM/32), blk, 0, stream>>>(Wo, WoT, DIM, DIM);
  k_transpose_cast<<<dim3(PFF/32, DIM/32), blk, 0, stream>>>(W1, W1T, DIM, PFF);
  k_transpose_cast<<<dim3(DIM/32, PFF/32), blk, 0, stream>>>(W2, W2T, PFF, DIM);
  k_pack3<<<dim3(12), blk, 0, stream>>>(bq, bk, bv, bqkv);

  // fused QKV GEMM: [4096][1024] x [3072][1024]^T -> [4096][3072] bf16
  k_gemm<false,true,true><<<dim3(NQKV/128, NROWS/128), blk, 0, stream>>>(
      Xbf, WqkvT, bqkv, QKV, NROWS, NQKV, DIM, DIM, DIM);
  k_rope<<<dim3(NROWS*512/256), blk, 0, stream>>>(QKV, rc, rsn);
  k_transpose_v<<<dim3(DIM/32, NROWS/32), blk, 0, stream>>>(QKV, VTb);
  k_attn<<<dim3(SEQ/128, NH, BATCH), blk, 0, stream>>>(QKV, VTb, xat);
  // Wo GEMM split-K=2 (grid 256->512, 2 blocks/CU)
  k_gemm<false,false,true ><<<dim3(DIM/128, NROWS/128), blk, 0, stream>>>(
      xat,       WoT,       bo, ao_a, NROWS, DIM, 512, DIM, DIM);
  k_gemm<false,false,false><<<dim3(DIM/128, NROWS/128), blk, 0, stream>>>(
      xat + 512, WoT + 512, nullptr, ao_b, NROWS, DIM, 512, DIM, DIM);
  k_ln3<true><<<dim3(NROWS), blk, 0, stream>>>(src, ao_a, ao_b, ln1g, ln1b, h, hbf);
  k_gemm<true,true,true><<<dim3(PFF/128, NROWS/128), blk, 0, stream>>>(
      hbf, W1T, b1, ff1, NROWS, PFF, DIM, DIM, DIM);
  // FF2 GEMM split-K=2 (grid 256->512)
  k_gemm<false,false,true ><<<dim3(DIM/128, NROWS/128), blk, 0, stream>>>(
      ff1,        W2T,        b2, ff2_a, NROWS, DIM, 2048, PFF, PFF);
  k_gemm<false,false,false><<<dim3(DIM/128, NROWS/128), blk, 0, stream>>>(
      ff1 + 2048, W2T + 2048, nullptr, ff2_b, NROWS, DIM, 2048, PFF, PFF);
  k_ln3<false><<<dim3(NROWS), blk, 0, stream>>>(h, ff2_a, ff2_b, ln2g, ln2b, (float*)d_out, nullptr);
}

// Round 6
// 285.196 us; speedup vs baseline: 1.1371x; 1.1371x over previous
//
#include <hip/hip_runtime.h>

#define SEQ 2048
#define DIM 1024
#define NH 16
#define HDIM 64
#define PFF 4096
#define NROWS 4096  // B*S
#define BATCH 2
#define NQKV 3072

typedef unsigned short u16;
typedef unsigned int u32;
typedef __attribute__((ext_vector_type(8))) short short8;
typedef __attribute__((ext_vector_type(4))) float f32x4;
typedef __attribute__((ext_vector_type(16))) float f32x16;

__device__ inline float b2f(u16 u){ return __uint_as_float(((u32)u)<<16); }
__device__ inline u16 f2b(float f){
  u32 u = __float_as_uint(f);
  u32 r = u + 0x7FFFu + ((u>>16)&1u);
  return (u16)(r>>16);
}

// C-style casts: clang allows addrspacecast via C-style cast (static_cast does not)
#define AS1C(p) ((const __attribute__((address_space(1))) unsigned int*)(p))
#define AS3P(p) ((__attribute__((address_space(3))) unsigned int*)(p))

// ---------------- elementwise cast fp32 -> bf16 (float4 per thread) ----------------
__global__ void k_cast_bf16(const float* __restrict__ in, u16* __restrict__ out, int n4){
  int i = blockIdx.x*256 + threadIdx.x;
  if (i >= n4) return;
  float4 v = ((const float4*)in)[i];
  ushort4 o;
  o.x = f2b(v.x); o.y = f2b(v.y); o.z = f2b(v.z); o.w = f2b(v.w);
  ((ushort4*)out)[i] = o;
}

// ---------------- transpose + cast: in fp32 [R][C] -> out bf16 [C][R] ----------------
__global__ __launch_bounds__(256) void k_transpose_cast(const float* __restrict__ in,
                                                        u16* __restrict__ out, int R, int C){
  __shared__ float tile[32][33];
  int tx = threadIdx.x & 31, ty = threadIdx.x >> 5;
  int c0 = blockIdx.x*32, r0 = blockIdx.y*32;
  #pragma unroll
  for (int i=0;i<4;++i)
    tile[ty+i*8][tx] = in[(size_t)(r0+ty+i*8)*C + c0 + tx];
  __syncthreads();
  #pragma unroll
  for (int i=0;i<4;++i)
    out[(size_t)(c0+ty+i*8)*R + r0 + tx] = f2b(tile[tx][ty+i*8]);
}

// ---------------- bf16 transpose: VT[d][r] = QKV[r][2048+d] ----------------
__global__ __launch_bounds__(256) void k_transpose_v(const u16* __restrict__ QKV, u16* __restrict__ VT){
  __shared__ u16 tile[32][34];
  int tx = threadIdx.x & 31, ty = threadIdx.x >> 5;
  int d0 = blockIdx.x*32, r0 = blockIdx.y*32;
  #pragma unroll
  for (int i=0;i<4;++i)
    tile[ty+i*8][tx] = QKV[(size_t)(r0+ty+i*8)*NQKV + 2048 + d0 + tx];
  __syncthreads();
  #pragma unroll
  for (int i=0;i<4;++i)
    VT[(size_t)(d0+ty+i*8)*NROWS + r0 + tx] = tile[tx][ty+i*8];
}

// ---------------- pack 3 bias vectors ----------------
__global__ void k_pack3(const float* __restrict__ a, const float* __restrict__ b,
                        const float* __restrict__ c, float* __restrict__ o){
  int i = blockIdx.x*256 + threadIdx.x;
  if (i >= NQKV) return;
  o[i] = i < 1024 ? a[i] : (i < 2048 ? b[i-1024] : c[i-2048]);
}

// ---------------- GEMM: C[M][N] = A[M][K](bf16) * Bt[N][K](bf16)^T (+ bias) ----------------
// 128x128 tile, BK=64, global_load_lds staging with pre-swizzled source (m173/m97).
// gridDim.z = concurrent split-K: block z covers K-range [z*Kc,(z+1)*Kc), writes its own
// fp32 partial at Cp + z*M*N; bias only on z==0.
template<bool RELU, bool BF16OUT, bool BIAS>
__global__ __launch_bounds__(256) void k_gemm(
    const u16* __restrict__ A, const u16* __restrict__ Bt,
    const float* __restrict__ bias, void* __restrict__ Cp,
    int M, int N, int Kc, int lda, int ldb){
  __shared__ __align__(16) char lds[32768];
  const int tid = threadIdx.x;
  const int lane = tid & 63, wid = tid >> 6;
  const int quad = lane >> 4, l15 = lane & 15;
  const int wr = wid >> 1, wc = wid & 1;
  const int rowBase = blockIdx.y * 128, colBase = blockIdx.x * 128;
  const u16* Az = A  + (size_t)blockIdx.z * Kc;
  const u16* Bz = Bt + (size_t)blockIdx.z * Kc;
  f32x4 acc[4][4] = {};
  const int srow = lane >> 3;
  const int scol = lane & 7;
  for (int k0 = 0; k0 < Kc; k0 += 64) {
    __syncthreads();
    #pragma unroll
    for (int i=0;i<4;++i){
      int wch = wid*4 + i;                // wave-chunk 0..15 (8 rows each)
      int row = wch*8 + srow;             // 0..127
      int c   = scol ^ (row & 7);         // pre-swizzled source chunk
      const u16* ga = Az + (size_t)(rowBase+row)*lda + k0 + c*8;
      __builtin_amdgcn_global_load_lds(AS1C(ga), AS3P(lds + wch*1024), 16, 0, 0);
      const u16* gb = Bz + (size_t)(colBase+row)*ldb + k0 + c*8;
      __builtin_amdgcn_global_load_lds(AS1C(gb), AS3P(lds + 16384 + wch*1024), 16, 0, 0);
    }
    __syncthreads();
    #pragma unroll
    for (int kk=0;kk<2;++kk){
      short8 af[4], bfr[4];
      #pragma unroll
      for (int m=0;m<4;++m){
        int r = wr*64 + m*16 + l15;
        af[m] = *(const short8*)(lds + ((r*128 + kk*64 + quad*16) ^ ((r&7)<<4)));
      }
      #pragma unroll
      for (int n=0;n<4;++n){
        int r = wc*64 + n*16 + l15;
        bfr[n] = *(const short8*)(lds + 16384 + ((r*128 + kk*64 + quad*16) ^ ((r&7)<<4)));
      }
      #pragma unroll
      for (int m=0;m<4;++m)
        #pragma unroll
        for (int n=0;n<4;++n)
          acc[m][n] = __builtin_amdgcn_mfma_f32_16x16x32_bf16(af[m], bfr[n], acc[m][n], 0,0,0);
    }
  }
  float* Cf = (float*)Cp + (size_t)blockIdx.z * M * N;
  #pragma unroll
  for (int m=0;m<4;++m){
    #pragma unroll
    for (int n=0;n<4;++n){
      int col = colBase + wc*64 + n*16 + l15;
      float bv = (BIAS && blockIdx.z == 0) ? bias[col] : 0.f;
      #pragma unroll
      for (int j=0;j<4;++j){
        int row = rowBase + wr*64 + m*16 + quad*4 + j;
        float v = acc[m][n][j] + bv;
        if (RELU) v = fmaxf(v, 0.f);
        if (BF16OUT) ((u16*)Cp)[(size_t)row*N + col] = f2b(v);
        else         Cf[(size_t)row*N + col] = v;
      }
    }
  }
}

// ---------------- RoPE in-place on fused QKV: Q cols scaled by 1/8, K cols ----------------
__global__ void k_rope(u16* __restrict__ QKV,
                       const float* __restrict__ cosT, const float* __restrict__ sinT){
  int idx = blockIdx.x*256 + threadIdx.x;   // NROWS*512 threads, one (q,k) pair each
  int row = idx >> 9, p = idx & 511;
  int s = row & (SEQ-1);
  float c = cosT[s*512 + p], sn = sinT[s*512 + p];
  u16* qp = QKV + (size_t)row*NQKV + 2*p;
  u16* kp = qp + 1024;
  ushort2 q = *(ushort2*)qp;
  ushort2 k = *(ushort2*)kp;
  float qx = b2f(q.x), qy = b2f(q.y), kx = b2f(k.x), ky = b2f(k.y);
  const float scale = 0.125f;   // 1/sqrt(HD)
  ushort2 qo, ko;
  qo.x = f2b((qx*c - qy*sn)*scale);
  qo.y = f2b((qx*sn + qy*c)*scale);
  ko.x = f2b(kx*c - ky*sn);
  ko.y = f2b(kx*sn + ky*c);
  *(ushort2*)qp = qo;
  *(ushort2*)kp = ko;
}

// ---------------- flash attention v3: swapped QK^T, in-reg softmax, 2-phase dbuf ----------------
// 4 warps x 32 q-rows (q-tile 128), KVBLK=64, mfma_32x32x16.
// LDS: 2 buffers x (K[64][64] swz | Vt[64][64] swz) = 32KB.
// Per tile: issue next tile's global_load_lds -> compute current -> one barrier (T3-minimum).
__global__ __launch_bounds__(256) void k_attn(
    const u16* __restrict__ QKV, const u16* __restrict__ VT, u16* __restrict__ Xo){
  const int qt = blockIdx.x, h = blockIdx.y, b = blockIdx.z;
  const int tid = threadIdx.x, lane = tid & 63, wid = tid >> 6;
  const int l31 = lane & 31, hi = lane >> 5;
  __shared__ __align__(16) char lds[32768];
  const int srow = lane >> 3, scol = lane & 7;

  // Q -> registers: qf[dk] = Q[q=qt*128+wid*32+l31][d=dk*16+8*hi .. +7]
  short8 qf[4];
  {
    const u16* qrow = QKV + (size_t)(b*SEQ + qt*128 + wid*32 + l31)*NQKV + h*HDIM;
    #pragma unroll
    for (int dk=0; dk<4; ++dk)
      qf[dk] = *(const short8*)(qrow + dk*16 + 8*hi);
  }
  float m_run = -1e30f, s_run = 0.f;
  f32x16 oacc[2] = {};
  const size_t krow0 = (size_t)(b*SEQ);

  auto do_stage = [&](int buf, int kt){
    char* kdst = lds + buf*16384;
    char* vdst = kdst + 8192;
    #pragma unroll
    for (int i=0;i<2;++i){
      int wch = wid*2 + i;           // 0..7 (8 rows each)
      int row = wch*8 + srow;
      int c = scol ^ (row & 7);
      const u16* gk = QKV + (krow0 + kt*64 + row)*NQKV + 1024 + h*HDIM + c*8;
      __builtin_amdgcn_global_load_lds(AS1C(gk), AS3P(kdst + wch*1024), 16, 0, 0);
      const u16* gv = VT + (size_t)(h*HDIM + row)*NROWS + b*SEQ + kt*64 + c*8;
      __builtin_amdgcn_global_load_lds(AS1C(gv), AS3P(vdst + wch*1024), 16, 0, 0);
    }
  };

  auto do_tile = [&](int buf){
    char* kb = lds + buf*16384;
    char* vb = kb + 8192;
    // ---- S^T = K Q^T : pacc[kb][r] = S[32kb+crow(r,hi)][q=l31]
    f32x16 pacc[2] = {};
    #pragma unroll
    for (int kbk=0;kbk<2;++kbk){
      #pragma unroll
      for (int dk=0;dk<4;++dk){
        int row = kbk*32 + l31;
        short8 kf = *(const short8*)(kb + ((row*128 + dk*32 + 16*hi) ^ ((row&7)<<4)));
        pacc[kbk] = __builtin_amdgcn_mfma_f32_32x32x16_bf16(kf, qf[dk], pacc[kbk], 0,0,0);
      }
    }
    // ---- tile max for q=l31 (in-register + partner half)
    float tmax = -1e30f;
    #pragma unroll
    for (int kbk=0;kbk<2;++kbk)
      #pragma unroll
      for (int r=0;r<16;++r) tmax = fmaxf(tmax, pacc[kbk][r]);
    tmax = fmaxf(tmax, __shfl_xor(tmax, 32));
    // ---- defer-max (T13): rescale only when growth > 8
    if (__any(tmax > m_run + 8.0f)){
      float mnew = fmaxf(m_run, tmax);
      float a = __expf(m_run - mnew);
      s_run *= a;
      m_run = mnew;
      #pragma unroll
      for (int r=0;r<16;++r){
        int src = (r&3) + 8*(r>>2) + 4*hi;   // q-row of acc reg r
        float ar = __shfl(a, src);
        oacc[0][r] *= ar;
        oacc[1][r] *= ar;
      }
    }
    // ---- P = exp(S - m_run), row-sum
    float p[2][16];
    float psum = 0.f;
    #pragma unroll
    for (int kbk=0;kbk<2;++kbk)
      #pragma unroll
      for (int r=0;r<16;++r){
        float e = __expf(pacc[kbk][r] - m_run);
        p[kbk][r] = e;
        psum += e;
      }
    psum += __shfl_xor(psum, 32);
    s_run += psum;
    // ---- pack P into PV A-fragments: pa[ks=2*kbk+s] (T12)
    short8 pa[4];
    #pragma unroll
    for (int kbk=0;kbk<2;++kbk){
      #pragma unroll
      for (int s=0;s<2;++s){
        u32 X0, X1, Y0, Y1;
        asm("v_cvt_pk_bf16_f32 %0, %1, %2" : "=v"(X0) : "v"(p[kbk][8*s+0]), "v"(p[kbk][8*s+1]));
        asm("v_cvt_pk_bf16_f32 %0, %1, %2" : "=v"(X1) : "v"(p[kbk][8*s+2]), "v"(p[kbk][8*s+3]));
        asm("v_cvt_pk_bf16_f32 %0, %1, %2" : "=v"(Y0) : "v"(p[kbk][8*s+4]), "v"(p[kbk][8*s+5]));
        asm("v_cvt_pk_bf16_f32 %0, %1, %2" : "=v"(Y1) : "v"(p[kbk][8*s+6]), "v"(p[kbk][8*s+7]));
        asm volatile("v_permlane32_swap_b32 %0, %1" : "+v"(X0), "+v"(Y0));
        asm volatile("v_permlane32_swap_b32 %0, %1" : "+v"(X1), "+v"(Y1));
        union { u32 w[4]; short8 s8; } pu;
        pu.w[0] = X0; pu.w[1] = X1; pu.w[2] = Y0; pu.w[3] = Y1;
        pa[2*kbk+s] = pu.s8;
      }
    }
    // ---- O += P V   (B-frag from Vt[d][k] tile)
    #pragma unroll
    for (int db=0;db<2;++db){
      #pragma unroll
      for (int ks=0;ks<4;++ks){
        int row = db*32 + l31;
        short8 vf = *(const short8*)(vb + ((row*128 + ks*32 + 16*hi) ^ ((row&7)<<4)));
        oacc[db] = __builtin_amdgcn_mfma_f32_32x32x16_bf16(pa[ks], vf, oacc[db], 0,0,0);
      }
    }
  };

  do_stage(0, 0);
  __syncthreads();
  const int NT = SEQ/64;
  #pragma unroll 1
  for (int kt=0; kt<NT; kt+=2){
    do_stage(1, kt+1);
    do_tile(0);
    __syncthreads();
    if (kt+2 < NT) do_stage(0, kt+2);
    do_tile(1);
    __syncthreads();
  }
  // ---- epilogue: divide by row-sum (redistribute s_run to acc rows), write out
  #pragma unroll
  for (int r=0;r<16;++r){
    int crow = (r&3) + 8*(r>>2) + 4*hi;
    float sq = __shfl(s_run, crow);
    float rs = __builtin_amdgcn_rcpf(sq);
    int grow = b*SEQ + qt*128 + wid*32 + crow;
    Xo[(size_t)grow*DIM + h*HDIM + l31]      = f2b(oacc[0][r] * rs);
    Xo[(size_t)grow*DIM + h*HDIM + 32 + l31] = f2b(oacc[1][r] * rs);
  }
}

// ---------------- residual + PARTS partials + layernorm (row per block) ----------------
template<int PARTS, bool WBF>
__global__ __launch_bounds__(256) void k_ln(
    const float* __restrict__ a, const float* __restrict__ p0, const float* __restrict__ p1,
    const float* __restrict__ p2, const float* __restrict__ p3,
    const float* __restrict__ g, const float* __restrict__ be,
    float* __restrict__ outf, u16* __restrict__ outb){
  const int row = blockIdx.x, tid = threadIdx.x;
  __shared__ float red[8];
  float4 av = ((const float4*)(a  + (size_t)row*DIM))[tid];
  float4 b0 = ((const float4*)(p0 + (size_t)row*DIM))[tid];
  float4 b1 = ((const float4*)(p1 + (size_t)row*DIM))[tid];
  float x0 = av.x+b0.x+b1.x, x1 = av.y+b0.y+b1.y, x2 = av.z+b0.z+b1.z, x3 = av.w+b0.w+b1.w;
  if constexpr (PARTS == 4){
    float4 b2v = ((const float4*)(p2 + (size_t)row*DIM))[tid];
    float4 b3v = ((const float4*)(p3 + (size_t)row*DIM))[tid];
    x0 += b2v.x+b3v.x; x1 += b2v.y+b3v.y; x2 += b2v.z+b3v.z; x3 += b2v.w+b3v.w;
  }
  float s = x0+x1+x2+x3;
  #pragma unroll
  for (int o=32;o>=1;o>>=1) s += __shfl_down(s, o);
  if ((tid&63)==0) red[tid>>6] = s;
  __syncthreads();
  float mean = (red[0]+red[1]+red[2]+red[3]) * (1.0f/DIM);
  float d0=x0-mean, d1=x1-mean, d2=x2-mean, d3=x3-mean;
  float vs = d0*d0+d1*d1+d2*d2+d3*d3;
  #pragma unroll
  for (int o=32;o>=1;o>>=1) vs += __shfl_down(vs, o);
  if ((tid&63)==0) red[4+(tid>>6)] = vs;
  __syncthreads();
  float var = (red[4]+red[5]+red[6]+red[7]) * (1.0f/DIM);
  float rs = rsqrtf(var + 1e-5f);
  float4 gv = ((const float4*)g)[tid];
  float4 bev = ((const float4*)be)[tid];
  float4 y;
  y.x = d0*rs*gv.x + bev.x;
  y.y = d1*rs*gv.y + bev.y;
  y.z = d2*rs*gv.z + bev.z;
  y.w = d3*rs*gv.w + bev.w;
  ((float4*)(outf + (size_t)row*DIM))[tid] = y;
  if (WBF){
    ushort4 o4; o4.x=f2b(y.x); o4.y=f2b(y.y); o4.z=f2b(y.z); o4.w=f2b(y.w);
    ((ushort4*)(outb + (size_t)row*DIM))[tid] = o4;
  }
}

extern "C" void kernel_launch(void* const* d_in, const int* in_sizes, int n_in,
                              void* d_out, int out_size, void* d_ws, size_t ws_size,
                              hipStream_t stream){
  (void)in_sizes; (void)n_in; (void)out_size; (void)ws_size;
  const float* src  = (const float*)d_in[0];
  const float* Wq   = (const float*)d_in[1];
  const float* bq   = (const float*)d_in[2];
  const float* Wk   = (const float*)d_in[3];
  const float* bk   = (const float*)d_in[4];
  const float* Wv   = (const float*)d_in[5];
  const float* bv   = (const float*)d_in[6];
  const float* Wo   = (const float*)d_in[7];
  const float* bo   = (const float*)d_in[8];
  const float* ln1g = (const float*)d_in[9];
  const float* ln1b = (const float*)d_in[10];
  const float* W1   = (const float*)d_in[11];
  const float* b1   = (const float*)d_in[12];
  const float* W2   = (const float*)d_in[13];
  const float* b2   = (const float*)d_in[14];
  const float* ln2g = (const float*)d_in[15];
  const float* ln2b = (const float*)d_in[16];
  const float* rc   = (const float*)d_in[17];
  const float* rsn  = (const float*)d_in[18];

  char* ws = (char*)d_ws;
  const size_t MB = (size_t)1<<20;
  // Region plan:
  //  0-8    Xbf (dead after QKV gemm)
  //  8-40   QKV(8-32)+VTb(32-40) during attn; then split-K partials:
  //         Wo: 2x16MB @8,24 | FF2: 4x16MB @8,24,40,56 (xat/hbf/WqkvT/WoT/W1T dead by then)
  //  40-48  xat | 48-56 hbf | 56-62 WqkvT | 62-64 WoT | 64-72 W1T | 72-80 W2T
  //  80-112 ff1 | 112-128 h | 128+ bqkv
  u16* Xbf   = (u16*)(ws);
  u16* QKV   = (u16*)(ws + 8*MB);
  u16* VTb   = (u16*)(ws + 32*MB);
  float* aop   = (float*)(ws + 8*MB);   // Wo partials: z at +z*16MB (8,24)
  float* ff2p  = (float*)(ws + 8*MB);   // FF2 partials: z at +z*16MB (8,24,40,56)
  u16* xat   = (u16*)(ws + 40*MB);
  u16* hbf   = (u16*)(ws + 48*MB);
  u16* WqkvT = (u16*)(ws + 56*MB);
  u16* WoT   = (u16*)(ws + 62*MB);
  u16* W1T   = (u16*)(ws + 64*MB);
  u16* W2T   = (u16*)(ws + 72*MB);
  u16* ff1   = (u16*)(ws + 80*MB);
  float* h   = (float*)(ws + 112*MB);
  float* bqkv= (float*)(ws + 128*MB);
  const size_t P16 = 16*MB/4;   // fp32 elements per 16MB partial

  dim3 blk(256);
  k_cast_bf16<<<dim3(NROWS*DIM/1024), blk, 0, stream>>>(src, Xbf, NROWS*DIM/4);
  k_transpose_cast<<<dim3(DIM/32, DIM/32), blk, 0, stream>>>(Wq, WqkvT, DIM, DIM);
  k_transpose_cast<<<dim3(DIM/32, DIM/32), blk, 0, stream>>>(Wk, WqkvT + (size_t)1024*1024, DIM, DIM);
  k_transpose_cast<<<dim3(DIM/32, DIM/32), blk, 0, stream>>>(Wv, WqkvT + (size_t)2048*1024, DIM, DIM);
  k_transpose_cast<<<dim3(DIM/32, DIM/32), blk, 0, stream>>>(Wo, WoT, DIM, DIM);
  k_transpose_cast<<<dim3(PFF/32, DIM/32), blk, 0, stream>>>(W1, W1T, DIM, PFF);
  k_transpose_cast<<<dim3(DIM/32, PFF/32), blk, 0, stream>>>(W2, W2T, PFF, DIM);
  k_pack3<<<dim3(12), blk, 0, stream>>>(bq, bk, bv, bqkv);

  // fused QKV GEMM: [4096][1024] x [3072][1024]^T -> [4096][3072] bf16
  k_gemm<false,true,true><<<dim3(NQKV/128, NROWS/128), blk, 0, stream>>>(
      Xbf, WqkvT, bqkv, QKV, NROWS, NQKV, DIM, DIM, DIM);
  k_rope<<<dim3(NROWS*512/256), blk, 0, stream>>>(QKV, rc, rsn);
  k_transpose_v<<<dim3(DIM/32, NROWS/32), blk, 0, stream>>>(QKV, VTb);
  k_attn<<<dim3(SEQ/128, NH, BATCH), blk, 0, stream>>>(QKV, VTb, xat);
  // Wo GEMM, concurrent split-K=2 (512 blocks)
  k_gemm<false,false,true><<<dim3(DIM/128, NROWS/128, 2), blk, 0, stream>>>(
      xat, WoT, bo, aop, NROWS, DIM, 512, DIM, DIM);
  k_ln<2,true><<<dim3(NROWS), blk, 0, stream>>>(src, aop, aop + P16, nullptr, nullptr,
                                                ln1g, ln1b, h, hbf);
  k_gemm<true,true,true><<<dim3(PFF/128, NROWS/128), blk, 0, stream>>>(
      hbf, W1T, b1, ff1, NROWS, PFF, DIM, DIM, DIM);
  // FF2 GEMM, concurrent split-K=4 (1024 blocks)
  k_gemm<false,false,true><<<dim3(DIM/128, NROWS/128, 4), blk, 0, stream>>>(
      ff1, W2T, b2, ff2p, NROWS, DIM, 1024, PFF, PFF);
  k_ln<4,false><<<dim3(NROWS), blk, 0, stream>>>(h, ff2p, ff2p + P16, ff2p + 2*P16, ff2p + 3*P16,
                                                 ln2g, ln2b, (float*)d_out, nullptr);
}

// Round 7
// 265.907 us; speedup vs baseline: 1.2196x; 1.0725x over previous
//
#include <hip/hip_runtime.h>

#define SEQ 2048
#define DIM 1024
#define NH 16
#define HDIM 64
#define PFF 4096
#define NROWS 4096  // B*S
#define BATCH 2
#define NQKV 3072

typedef unsigned short u16;
typedef unsigned int u32;
typedef __attribute__((ext_vector_type(8))) short short8;
typedef __attribute__((ext_vector_type(4))) float f32x4;
typedef __attribute__((ext_vector_type(16))) float f32x16;

__device__ inline float b2f(u16 u){ return __uint_as_float(((u32)u)<<16); }
__device__ inline u16 f2b(float f){
  u32 u = __float_as_uint(f);
  u32 r = u + 0x7FFFu + ((u>>16)&1u);
  return (u16)(r>>16);
}

// C-style casts: clang allows addrspacecast via C-style cast (static_cast does not)
#define AS1C(p) ((const __attribute__((address_space(1))) unsigned int*)(p))
#define AS3P(p) ((__attribute__((address_space(3))) unsigned int*)(p))

// ---------------- elementwise cast fp32 -> bf16 (float4 per thread) ----------------
__global__ void k_cast_bf16(const float* __restrict__ in, u16* __restrict__ out, int n4){
  int i = blockIdx.x*256 + threadIdx.x;
  if (i >= n4) return;
  float4 v = ((const float4*)in)[i];
  ushort4 o;
  o.x = f2b(v.x); o.y = f2b(v.y); o.z = f2b(v.z); o.w = f2b(v.w);
  ((ushort4*)out)[i] = o;
}

// ---------------- transpose + cast: in fp32 [R][C] -> out bf16 [C][R] ----------------
__global__ __launch_bounds__(256) void k_transpose_cast(const float* __restrict__ in,
                                                        u16* __restrict__ out, int R, int C){
  __shared__ float tile[32][33];
  int tx = threadIdx.x & 31, ty = threadIdx.x >> 5;
  int c0 = blockIdx.x*32, r0 = blockIdx.y*32;
  #pragma unroll
  for (int i=0;i<4;++i)
    tile[ty+i*8][tx] = in[(size_t)(r0+ty+i*8)*C + c0 + tx];
  __syncthreads();
  #pragma unroll
  for (int i=0;i<4;++i)
    out[(size_t)(c0+ty+i*8)*R + r0 + tx] = f2b(tile[tx][ty+i*8]);
}

// ---------------- bf16 transpose: VT[d][r] = QKV[r][2048+d] ----------------
__global__ __launch_bounds__(256) void k_transpose_v(const u16* __restrict__ QKV, u16* __restrict__ VT){
  __shared__ u16 tile[32][34];
  int tx = threadIdx.x & 31, ty = threadIdx.x >> 5;
  int d0 = blockIdx.x*32, r0 = blockIdx.y*32;
  #pragma unroll
  for (int i=0;i<4;++i)
    tile[ty+i*8][tx] = QKV[(size_t)(r0+ty+i*8)*NQKV + 2048 + d0 + tx];
  __syncthreads();
  #pragma unroll
  for (int i=0;i<4;++i)
    VT[(size_t)(d0+ty+i*8)*NROWS + r0 + tx] = tile[tx][ty+i*8];
}

// ---------------- pack 3 bias vectors ----------------
__global__ void k_pack3(const float* __restrict__ a, const float* __restrict__ b,
                        const float* __restrict__ c, float* __restrict__ o){
  int i = blockIdx.x*256 + threadIdx.x;
  if (i >= NQKV) return;
  o[i] = i < 1024 ? a[i] : (i < 2048 ? b[i-1024] : c[i-2048]);
}

// ---------------- GEMM: C[M][N] = A[M][K](bf16) * Bt[N][K](bf16)^T (+ bias) ----------------
// 128x128 tile, BK=64, global_load_lds staging with pre-swizzled source (m173/m97).
// XCD-chunked blockIdx swizzle (T1/m157; requires gridDim.x*gridDim.y % 8 == 0 - all our grids).
// gridDim.z = concurrent split-K: block z covers K-range [z*Kc,(z+1)*Kc), writes its own
// fp32 partial at Cp + z*M*N; bias only on z==0.
template<bool RELU, bool BF16OUT, bool BIAS>
__global__ __launch_bounds__(256) void k_gemm(
    const u16* __restrict__ A, const u16* __restrict__ Bt,
    const float* __restrict__ bias, void* __restrict__ Cp,
    int M, int N, int Kc, int lda, int ldb){
  __shared__ __align__(16) char lds[32768];
  const int tid = threadIdx.x;
  const int lane = tid & 63, wid = tid >> 6;
  const int quad = lane >> 4, l15 = lane & 15;
  const int wr = wid >> 1, wc = wid & 1;
  // XCD-chunk swizzle: physical linear id -> logical tile so each XCD owns a
  // contiguous chunk of the (x,y) space (A-panel L2 locality).
  const int nwg = gridDim.x * gridDim.y;
  int lid = blockIdx.y * gridDim.x + blockIdx.x;
  lid = (lid & 7) * (nwg >> 3) + (lid >> 3);
  const int bx = lid % gridDim.x, by = lid / gridDim.x;
  const int rowBase = by * 128, colBase = bx * 128;
  const u16* Az = A  + (size_t)blockIdx.z * Kc;
  const u16* Bz = Bt + (size_t)blockIdx.z * Kc;
  f32x4 acc[4][4] = {};
  const int srow = lane >> 3;
  const int scol = lane & 7;
  for (int k0 = 0; k0 < Kc; k0 += 64) {
    __syncthreads();
    #pragma unroll
    for (int i=0;i<4;++i){
      int wch = wid*4 + i;                // wave-chunk 0..15 (8 rows each)
      int row = wch*8 + srow;             // 0..127
      int c   = scol ^ (row & 7);         // pre-swizzled source chunk
      const u16* ga = Az + (size_t)(rowBase+row)*lda + k0 + c*8;
      __builtin_amdgcn_global_load_lds(AS1C(ga), AS3P(lds + wch*1024), 16, 0, 0);
      const u16* gb = Bz + (size_t)(colBase+row)*ldb + k0 + c*8;
      __builtin_amdgcn_global_load_lds(AS1C(gb), AS3P(lds + 16384 + wch*1024), 16, 0, 0);
    }
    __syncthreads();
    #pragma unroll
    for (int kk=0;kk<2;++kk){
      short8 af[4], bfr[4];
      #pragma unroll
      for (int m=0;m<4;++m){
        int r = wr*64 + m*16 + l15;
        af[m] = *(const short8*)(lds + ((r*128 + kk*64 + quad*16) ^ ((r&7)<<4)));
      }
      #pragma unroll
      for (int n=0;n<4;++n){
        int r = wc*64 + n*16 + l15;
        bfr[n] = *(const short8*)(lds + 16384 + ((r*128 + kk*64 + quad*16) ^ ((r&7)<<4)));
      }
      __builtin_amdgcn_s_setprio(1);
      #pragma unroll
      for (int m=0;m<4;++m)
        #pragma unroll
        for (int n=0;n<4;++n)
          acc[m][n] = __builtin_amdgcn_mfma_f32_16x16x32_bf16(af[m], bfr[n], acc[m][n], 0,0,0);
      __builtin_amdgcn_s_setprio(0);
    }
  }
  float* Cf = (float*)Cp + (size_t)blockIdx.z * M * N;
  #pragma unroll
  for (int m=0;m<4;++m){
    #pragma unroll
    for (int n=0;n<4;++n){
      int col = colBase + wc*64 + n*16 + l15;
      float bv = (BIAS && blockIdx.z == 0) ? bias[col] : 0.f;
      #pragma unroll
      for (int j=0;j<4;++j){
        int row = rowBase + wr*64 + m*16 + quad*4 + j;
        float v = acc[m][n][j] + bv;
        if (RELU) v = fmaxf(v, 0.f);
        if (BF16OUT) ((u16*)Cp)[(size_t)row*N + col] = f2b(v);
        else         Cf[(size_t)row*N + col] = v;
      }
    }
  }
}

// ---------------- RoPE in-place on fused QKV: Q cols scaled by 1/8, K cols ----------------
__global__ void k_rope(u16* __restrict__ QKV,
                       const float* __restrict__ cosT, const float* __restrict__ sinT){
  int idx = blockIdx.x*256 + threadIdx.x;   // NROWS*512 threads, one (q,k) pair each
  int row = idx >> 9, p = idx & 511;
  int s = row & (SEQ-1);
  float c = cosT[s*512 + p], sn = sinT[s*512 + p];
  u16* qp = QKV + (size_t)row*NQKV + 2*p;
  u16* kp = qp + 1024;
  ushort2 q = *(ushort2*)qp;
  ushort2 k = *(ushort2*)kp;
  float qx = b2f(q.x), qy = b2f(q.y), kx = b2f(k.x), ky = b2f(k.y);
  const float scale = 0.125f;   // 1/sqrt(HD)
  ushort2 qo, ko;
  qo.x = f2b((qx*c - qy*sn)*scale);
  qo.y = f2b((qx*sn + qy*c)*scale);
  ko.x = f2b(kx*c - ky*sn);
  ko.y = f2b(kx*sn + ky*c);
  *(ushort2*)qp = qo;
  *(ushort2*)kp = ko;
}

// ---------------- flash attention v3: swapped QK^T, in-reg softmax, 2-phase dbuf ----------------
// 4 warps x 32 q-rows (q-tile 128), KVBLK=64, mfma_32x32x16.
// LDS: 2 buffers x (K[64][64] swz | Vt[64][64] swz) = 32KB.
// Per tile: issue next tile's global_load_lds -> compute current -> one barrier (T3-minimum).
__global__ __launch_bounds__(256) void k_attn(
    const u16* __restrict__ QKV, const u16* __restrict__ VT, u16* __restrict__ Xo){
  const int qt = blockIdx.x, h = blockIdx.y, b = blockIdx.z;
  const int tid = threadIdx.x, lane = tid & 63, wid = tid >> 6;
  const int l31 = lane & 31, hi = lane >> 5;
  __shared__ __align__(16) char lds[32768];
  const int srow = lane >> 3, scol = lane & 7;

  // Q -> registers: qf[dk] = Q[q=qt*128+wid*32+l31][d=dk*16+8*hi .. +7]
  short8 qf[4];
  {
    const u16* qrow = QKV + (size_t)(b*SEQ + qt*128 + wid*32 + l31)*NQKV + h*HDIM;
    #pragma unroll
    for (int dk=0; dk<4; ++dk)
      qf[dk] = *(const short8*)(qrow + dk*16 + 8*hi);
  }
  float m_run = -1e30f, s_run = 0.f;
  f32x16 oacc[2] = {};
  const size_t krow0 = (size_t)(b*SEQ);

  auto do_stage = [&](int buf, int kt){
    char* kdst = lds + buf*16384;
    char* vdst = kdst + 8192;
    #pragma unroll
    for (int i=0;i<2;++i){
      int wch = wid*2 + i;           // 0..7 (8 rows each)
      int row = wch*8 + srow;
      int c = scol ^ (row & 7);
      const u16* gk = QKV + (krow0 + kt*64 + row)*NQKV + 1024 + h*HDIM + c*8;
      __builtin_amdgcn_global_load_lds(AS1C(gk), AS3P(kdst + wch*1024), 16, 0, 0);
      const u16* gv = VT + (size_t)(h*HDIM + row)*NROWS + b*SEQ + kt*64 + c*8;
      __builtin_amdgcn_global_load_lds(AS1C(gv), AS3P(vdst + wch*1024), 16, 0, 0);
    }
  };

  auto do_tile = [&](int buf){
    char* kb = lds + buf*16384;
    char* vb = kb + 8192;
    // ---- S^T = K Q^T : pacc[kb][r] = S[32kb+crow(r,hi)][q=l31]
    f32x16 pacc[2] = {};
    __builtin_amdgcn_s_setprio(1);
    #pragma unroll
    for (int kbk=0;kbk<2;++kbk){
      #pragma unroll
      for (int dk=0;dk<4;++dk){
        int row = kbk*32 + l31;
        short8 kf = *(const short8*)(kb + ((row*128 + dk*32 + 16*hi) ^ ((row&7)<<4)));
        pacc[kbk] = __builtin_amdgcn_mfma_f32_32x32x16_bf16(kf, qf[dk], pacc[kbk], 0,0,0);
      }
    }
    __builtin_amdgcn_s_setprio(0);
    // ---- tile max for q=l31 (in-register + partner half)
    float tmax = -1e30f;
    #pragma unroll
    for (int kbk=0;kbk<2;++kbk)
      #pragma unroll
      for (int r=0;r<16;++r) tmax = fmaxf(tmax, pacc[kbk][r]);
    tmax = fmaxf(tmax, __shfl_xor(tmax, 32));
    // ---- defer-max (T13): rescale only when growth > 8
    if (__any(tmax > m_run + 8.0f)){
      float mnew = fmaxf(m_run, tmax);
      float a = __expf(m_run - mnew);
      s_run *= a;
      m_run = mnew;
      #pragma unroll
      for (int r=0;r<16;++r){
        int src = (r&3) + 8*(r>>2) + 4*hi;   // q-row of acc reg r
        float ar = __shfl(a, src);
        oacc[0][r] *= ar;
        oacc[1][r] *= ar;
      }
    }
    // ---- P = exp(S - m_run), row-sum
    float p[2][16];
    float psum = 0.f;
    #pragma unroll
    for (int kbk=0;kbk<2;++kbk)
      #pragma unroll
      for (int r=0;r<16;++r){
        float e = __expf(pacc[kbk][r] - m_run);
        p[kbk][r] = e;
        psum += e;
      }
    psum += __shfl_xor(psum, 32);
    s_run += psum;
    // ---- pack P into PV A-fragments: pa[ks=2*kbk+s] (T12)
    short8 pa[4];
    #pragma unroll
    for (int kbk=0;kbk<2;++kbk){
      #pragma unroll
      for (int s=0;s<2;++s){
        u32 X0, X1, Y0, Y1;
        asm("v_cvt_pk_bf16_f32 %0, %1, %2" : "=v"(X0) : "v"(p[kbk][8*s+0]), "v"(p[kbk][8*s+1]));
        asm("v_cvt_pk_bf16_f32 %0, %1, %2" : "=v"(X1) : "v"(p[kbk][8*s+2]), "v"(p[kbk][8*s+3]));
        asm("v_cvt_pk_bf16_f32 %0, %1, %2" : "=v"(Y0) : "v"(p[kbk][8*s+4]), "v"(p[kbk][8*s+5]));
        asm("v_cvt_pk_bf16_f32 %0, %1, %2" : "=v"(Y1) : "v"(p[kbk][8*s+6]), "v"(p[kbk][8*s+7]));
        asm volatile("v_permlane32_swap_b32 %0, %1" : "+v"(X0), "+v"(Y0));
        asm volatile("v_permlane32_swap_b32 %0, %1" : "+v"(X1), "+v"(Y1));
        union { u32 w[4]; short8 s8; } pu;
        pu.w[0] = X0; pu.w[1] = X1; pu.w[2] = Y0; pu.w[3] = Y1;
        pa[2*kbk+s] = pu.s8;
      }
    }
    // ---- O += P V   (B-frag from Vt[d][k] tile)
    __builtin_amdgcn_s_setprio(1);
    #pragma unroll
    for (int db=0;db<2;++db){
      #pragma unroll
      for (int ks=0;ks<4;++ks){
        int row = db*32 + l31;
        short8 vf = *(const short8*)(vb + ((row*128 + ks*32 + 16*hi) ^ ((row&7)<<4)));
        oacc[db] = __builtin_amdgcn_mfma_f32_32x32x16_bf16(pa[ks], vf, oacc[db], 0,0,0);
      }
    }
    __builtin_amdgcn_s_setprio(0);
  };

  do_stage(0, 0);
  __syncthreads();
  const int NT = SEQ/64;
  #pragma unroll 1
  for (int kt=0; kt<NT; kt+=2){
    do_stage(1, kt+1);
    do_tile(0);
    __syncthreads();
    if (kt+2 < NT) do_stage(0, kt+2);
    do_tile(1);
    __syncthreads();
  }
  // ---- epilogue: divide by row-sum (redistribute s_run to acc rows), write out
  #pragma unroll
  for (int r=0;r<16;++r){
    int crow = (r&3) + 8*(r>>2) + 4*hi;
    float sq = __shfl(s_run, crow);
    float rs = __builtin_amdgcn_rcpf(sq);
    int grow = b*SEQ + qt*128 + wid*32 + crow;
    Xo[(size_t)grow*DIM + h*HDIM + l31]      = f2b(oacc[0][r] * rs);
    Xo[(size_t)grow*DIM + h*HDIM + 32 + l31] = f2b(oacc[1][r] * rs);
  }
}

// ---------------- residual + PARTS partials + layernorm (row per block) ----------------
template<int PARTS, bool WBF>
__global__ __launch_bounds__(256) void k_ln(
    const float* __restrict__ a, const float* __restrict__ p0, const float* __restrict__ p1,
    const float* __restrict__ p2, const float* __restrict__ p3,
    const float* __restrict__ g, const float* __restrict__ be,
    float* __restrict__ outf, u16* __restrict__ outb){
  const int row = blockIdx.x, tid = threadIdx.x;
  __shared__ float red[8];
  float4 av = ((const float4*)(a  + (size_t)row*DIM))[tid];
  float4 b0 = ((const float4*)(p0 + (size_t)row*DIM))[tid];
  float4 b1 = ((const float4*)(p1 + (size_t)row*DIM))[tid];
  float x0 = av.x+b0.x+b1.x, x1 = av.y+b0.y+b1.y, x2 = av.z+b0.z+b1.z, x3 = av.w+b0.w+b1.w;
  if constexpr (PARTS == 4){
    float4 b2v = ((const float4*)(p2 + (size_t)row*DIM))[tid];
    float4 b3v = ((const float4*)(p3 + (size_t)row*DIM))[tid];
    x0 += b2v.x+b3v.x; x1 += b2v.y+b3v.y; x2 += b2v.z+b3v.z; x3 += b2v.w+b3v.w;
  }
  float s = x0+x1+x2+x3;
  #pragma unroll
  for (int o=32;o>=1;o>>=1) s += __shfl_down(s, o);
  if ((tid&63)==0) red[tid>>6] = s;
  __syncthreads();
  float mean = (red[0]+red[1]+red[2]+red[3]) * (1.0f/DIM);
  float d0=x0-mean, d1=x1-mean, d2=x2-mean, d3=x3-mean;
  float vs = d0*d0+d1*d1+d2*d2+d3*d3;
  #pragma unroll
  for (int o=32;o>=1;o>>=1) vs += __shfl_down(vs, o);
  if ((tid&63)==0) red[4+(tid>>6)] = vs;
  __syncthreads();
  float var = (red[4]+red[5]+red[6]+red[7]) * (1.0f/DIM);
  float rs = rsqrtf(var + 1e-5f);
  float4 gv = ((const float4*)g)[tid];
  float4 bev = ((const float4*)be)[tid];
  float4 y;
  y.x = d0*rs*gv.x + bev.x;
  y.y = d1*rs*gv.y + bev.y;
  y.z = d2*rs*gv.z + bev.z;
  y.w = d3*rs*gv.w + bev.w;
  ((float4*)(outf + (size_t)row*DIM))[tid] = y;
  if (WBF){
    ushort4 o4; o4.x=f2b(y.x); o4.y=f2b(y.y); o4.z=f2b(y.z); o4.w=f2b(y.w);
    ((ushort4*)(outb + (size_t)row*DIM))[tid] = o4;
  }
}

extern "C" void kernel_launch(void* const* d_in, const int* in_sizes, int n_in,
                              void* d_out, int out_size, void* d_ws, size_t ws_size,
                              hipStream_t stream){
  (void)in_sizes; (void)n_in; (void)out_size; (void)ws_size;
  const float* src  = (const float*)d_in[0];
  const float* Wq   = (const float*)d_in[1];
  const float* bq   = (const float*)d_in[2];
  const float* Wk   = (const float*)d_in[3];
  const float* bk   = (const float*)d_in[4];
  const float* Wv   = (const float*)d_in[5];
  const float* bv   = (const float*)d_in[6];
  const float* Wo   = (const float*)d_in[7];
  const float* bo   = (const float*)d_in[8];
  const float* ln1g = (const float*)d_in[9];
  const float* ln1b = (const float*)d_in[10];
  const float* W1   = (const float*)d_in[11];
  const float* b1   = (const float*)d_in[12];
  const float* W2   = (const float*)d_in[13];
  const float* b2   = (const float*)d_in[14];
  const float* ln2g = (const float*)d_in[15];
  const float* ln2b = (const float*)d_in[16];
  const float* rc   = (const float*)d_in[17];
  const float* rsn  = (const float*)d_in[18];

  char* ws = (char*)d_ws;
  const size_t MB = (size_t)1<<20;
  // Region plan:
  //  0-8    Xbf (dead after QKV gemm)
  //  8-40   QKV(8-32)+VTb(32-40) during attn; then split-K partials:
  //         Wo: 2x16MB @8,24 | FF2: 2x16MB @8,24
  //  40-48  xat | 48-56 hbf | 56-62 WqkvT | 62-64 WoT | 64-72 W1T | 72-80 W2T
  //  80-112 ff1 | 112-128 h | 128+ bqkv
  u16* Xbf   = (u16*)(ws);
  u16* QKV   = (u16*)(ws + 8*MB);
  u16* VTb   = (u16*)(ws + 32*MB);
  float* aop   = (float*)(ws + 8*MB);   // Wo partials: z at +z*16MB
  float* ff2p  = (float*)(ws + 8*MB);   // FF2 partials: z at +z*16MB
  u16* xat   = (u16*)(ws + 40*MB);
  u16* hbf   = (u16*)(ws + 48*MB);
  u16* WqkvT = (u16*)(ws + 56*MB);
  u16* WoT   = (u16*)(ws + 62*MB);
  u16* W1T   = (u16*)(ws + 64*MB);
  u16* W2T   = (u16*)(ws + 72*MB);
  u16* ff1   = (u16*)(ws + 80*MB);
  float* h   = (float*)(ws + 112*MB);
  float* bqkv= (float*)(ws + 128*MB);
  const size_t P16 = 16*MB/4;   // fp32 elements per 16MB partial

  dim3 blk(256);
  k_cast_bf16<<<dim3(NROWS*DIM/1024), blk, 0, stream>>>(src, Xbf, NROWS*DIM/4);
  k_transpose_cast<<<dim3(DIM/32, DIM/32), blk, 0, stream>>>(Wq, WqkvT, DIM, DIM);
  k_transpose_cast<<<dim3(DIM/32, DIM/32), blk, 0, stream>>>(Wk, WqkvT + (size_t)1024*1024, DIM, DIM);
  k_transpose_cast<<<dim3(DIM/32, DIM/32), blk, 0, stream>>>(Wv, WqkvT + (size_t)2048*1024, DIM, DIM);
  k_transpose_cast<<<dim3(DIM/32, DIM/32), blk, 0, stream>>>(Wo, WoT, DIM, DIM);
  k_transpose_cast<<<dim3(PFF/32, DIM/32), blk, 0, stream>>>(W1, W1T, DIM, PFF);
  k_transpose_cast<<<dim3(DIM/32, PFF/32), blk, 0, stream>>>(W2, W2T, PFF, DIM);
  k_pack3<<<dim3(12), blk, 0, stream>>>(bq, bk, bv, bqkv);

  // fused QKV GEMM: [4096][1024] x [3072][1024]^T -> [4096][3072] bf16
  k_gemm<false,true,true><<<dim3(NQKV/128, NROWS/128), blk, 0, stream>>>(
      Xbf, WqkvT, bqkv, QKV, NROWS, NQKV, DIM, DIM, DIM);
  k_rope<<<dim3(NROWS*512/256), blk, 0, stream>>>(QKV, rc, rsn);
  k_transpose_v<<<dim3(DIM/32, NROWS/32), blk, 0, stream>>>(QKV, VTb);
  k_attn<<<dim3(SEQ/128, NH, BATCH), blk, 0, stream>>>(QKV, VTb, xat);
  // Wo GEMM, concurrent split-K=2 (512 blocks)
  k_gemm<false,false,true><<<dim3(DIM/128, NROWS/128, 2), blk, 0, stream>>>(
      xat, WoT, bo, aop, NROWS, DIM, 512, DIM, DIM);
  k_ln<2,true><<<dim3(NROWS), blk, 0, stream>>>(src, aop, aop + P16, nullptr, nullptr,
                                                ln1g, ln1b, h, hbf);
  k_gemm<true,true,true><<<dim3(PFF/128, NROWS/128), blk, 0, stream>>>(
      hbf, W1T, b1, ff1, NROWS, PFF, DIM, DIM, DIM);
  // FF2 GEMM, concurrent split-K=2 (512 blocks, Kc=2048)
  k_gemm<false,false,true><<<dim3(DIM/128, NROWS/128, 2), blk, 0, stream>>>(
      ff1, W2T, b2, ff2p, NROWS, DIM, 2048, PFF, PFF);
  k_ln<2,false><<<dim3(NROWS), blk, 0, stream>>>(h, ff2p, ff2p + P16, nullptr, nullptr,
                                                 ln2g, ln2b, (float*)d_out, nullptr);
}

// Round 8
// 255.365 us; speedup vs baseline: 1.2699x; 1.0413x over previous
//
#include <hip/hip_runtime.h>

#define SEQ 2048
#define DIM 1024
#define NH 16
#define HDIM 64
#define PFF 4096
#define NROWS 4096  // B*S
#define BATCH 2
#define NQKV 3072

typedef unsigned short u16;
typedef unsigned int u32;
typedef __attribute__((ext_vector_type(8))) short short8;
typedef __attribute__((ext_vector_type(4))) float f32x4;
typedef __attribute__((ext_vector_type(16))) float f32x16;

__device__ inline float b2f(u16 u){ return __uint_as_float(((u32)u)<<16); }
__device__ inline u16 f2b(float f){
  u32 u = __float_as_uint(f);
  u32 r = u + 0x7FFFu + ((u>>16)&1u);
  return (u16)(r>>16);
}

// C-style casts: clang allows addrspacecast via C-style cast (static_cast does not)
#define AS1C(p) ((const __attribute__((address_space(1))) unsigned int*)(p))
#define AS3P(p) ((__attribute__((address_space(3))) unsigned int*)(p))

// ---------------- elementwise cast fp32 -> bf16 (float4 per thread) ----------------
__global__ void k_cast_bf16(const float* __restrict__ in, u16* __restrict__ out, int n4){
  int i = blockIdx.x*256 + threadIdx.x;
  if (i >= n4) return;
  float4 v = ((const float4*)in)[i];
  ushort4 o;
  o.x = f2b(v.x); o.y = f2b(v.y); o.z = f2b(v.z); o.w = f2b(v.w);
  ((ushort4*)out)[i] = o;
}

// ---------------- transpose + cast: in fp32 [R][C] -> out bf16 [C][R] ----------------
__global__ __launch_bounds__(256) void k_transpose_cast(const float* __restrict__ in,
                                                        u16* __restrict__ out, int R, int C){
  __shared__ float tile[32][33];
  int tx = threadIdx.x & 31, ty = threadIdx.x >> 5;
  int c0 = blockIdx.x*32, r0 = blockIdx.y*32;
  #pragma unroll
  for (int i=0;i<4;++i)
    tile[ty+i*8][tx] = in[(size_t)(r0+ty+i*8)*C + c0 + tx];
  __syncthreads();
  #pragma unroll
  for (int i=0;i<4;++i)
    out[(size_t)(c0+ty+i*8)*R + r0 + tx] = f2b(tile[tx][ty+i*8]);
}

// ---------------- bf16 transpose: VT[d][r] = QKV[r][2048+d] ----------------
__global__ __launch_bounds__(256) void k_transpose_v(const u16* __restrict__ QKV, u16* __restrict__ VT){
  __shared__ u16 tile[32][34];
  int tx = threadIdx.x & 31, ty = threadIdx.x >> 5;
  int d0 = blockIdx.x*32, r0 = blockIdx.y*32;
  #pragma unroll
  for (int i=0;i<4;++i)
    tile[ty+i*8][tx] = QKV[(size_t)(r0+ty+i*8)*NQKV + 2048 + d0 + tx];
  __syncthreads();
  #pragma unroll
  for (int i=0;i<4;++i)
    VT[(size_t)(d0+ty+i*8)*NROWS + r0 + tx] = tile[tx][ty+i*8];
}

// ---------------- pack 3 bias vectors ----------------
__global__ void k_pack3(const float* __restrict__ a, const float* __restrict__ b,
                        const float* __restrict__ c, float* __restrict__ o){
  int i = blockIdx.x*256 + threadIdx.x;
  if (i >= NQKV) return;
  o[i] = i < 1024 ? a[i] : (i < 2048 ? b[i-1024] : c[i-2048]);
}

// ================= 8-phase 256x256 GEMM (T2+T3+T4+T5 stack, m201-style) =================
// 512 threads = 8 waves (2M x 4N). BK=64. LDS = 2 bufs x (A 32KB + B 32KB) = 128KB dynamic.
// LDS layout: 1024B subtiles of [16 rows][32 k]; subtile idx = rs*2+ks; slot l = row (l>>2),
// k-chunk (l&3)*8. One wave's global_load_lds stages exactly one subtile (linear dest, m104-safe);
// frag read (l15*4+quad)*16 walks the subtile contiguously -> conflict-free both sides (rule 21).
// Per K-tile: 4 phases (quadrants m0n0,m0n1,m1n1,m1n0), 16 MFMA each in setprio(1) (T5),
// 2 barriers/phase; next tile staged front-loaded in phases 1-2; vmcnt(0) at phase-4 start (T4).
template<bool RELU, bool BF16OUT>
__global__ __launch_bounds__(512, 2) void k_gemm256(
    const u16* __restrict__ A, const u16* __restrict__ Bt,
    const float* __restrict__ bias, void* __restrict__ Cp,
    int M, int N, int K, int lda, int ldb){
  extern __shared__ char lds[];
  const int tid = threadIdx.x;
  const int lane = tid & 63, wid = tid >> 6;
  const int quad = lane >> 4, l15 = lane & 15;
  const int wm = wid >> 2, wn = wid & 3;
  const int ro = (l15*4 + quad)*16;        // in-subtile frag offset
  const int srow = lane >> 2;              // staging: row within subtile
  const int sk   = (lane & 3)*8;           // staging: k within subtile
  // XCD-chunk swizzle (bijective: nwg % 8 == 0 for all our grids)
  const int nwg = gridDim.x * gridDim.y;
  int lid = blockIdx.y * gridDim.x + blockIdx.x;
  lid = (lid & 7) * (nwg >> 3) + (lid >> 3);
  const int bx = lid % gridDim.x, by = lid / gridDim.x;
  const int rowBase = by*256, colBase = bx*256;

  f32x4 acc[8][4] = {};

  auto stage2 = [&](int buf, int k0, int i){   // stage A-issue i and B-issue i (1 subtile each/wave)
    int idx = i*8 + wid;                       // 0..31
    int rs = idx >> 1, ks = idx & 1;
    const u16* ga = A + (size_t)(rowBase + rs*16 + srow)*lda + k0 + ks*32 + sk;
    __builtin_amdgcn_global_load_lds(AS1C(ga), AS3P(lds + buf*65536 + idx*1024), 16, 0, 0);
    const u16* gb = Bt + (size_t)(colBase + rs*16 + srow)*ldb + k0 + ks*32 + sk;
    __builtin_amdgcn_global_load_lds(AS1C(gb), AS3P(lds + buf*65536 + 32768 + idx*1024), 16, 0, 0);
  };

  // prologue: stage tile 0
  #pragma unroll
  for (int i=0;i<4;++i) stage2(0, 0, i);
  __syncthreads();

  const int NT = K >> 6;
  #pragma unroll 1
  for (int t=0; t<NT; ++t){
    const int buf = t & 1;
    const bool pf = (t+1 < NT);
    const int k0n = (t+1)*64;
    char* Ab = lds + buf*65536;
    char* Bb = Ab + 32768;
    short8 a0[4][2], a1[4][2], b0[2][2], b1[2][2];

    // ---- phase 1: load A(m-half0)+B(n-half0); stage issues 0,1; MFMA m0n0
    #pragma unroll
    for (int mf=0; mf<4; ++mf)
      #pragma unroll
      for (int kk=0; kk<2; ++kk)
        a0[mf][kk] = *(const short8*)(Ab + ((wm*8+mf)*2+kk)*1024 + ro);
    #pragma unroll
    for (int nf=0; nf<2; ++nf)
      #pragma unroll
      for (int kk=0; kk<2; ++kk)
        b0[nf][kk] = *(const short8*)(Bb + ((wn*4+nf)*2+kk)*1024 + ro);
    if (pf){ stage2(buf^1, k0n, 0); stage2(buf^1, k0n, 1); }
    __builtin_amdgcn_s_barrier();
    __builtin_amdgcn_s_setprio(1);
    #pragma unroll
    for (int mf=0; mf<4; ++mf)
      #pragma unroll
      for (int nf=0; nf<2; ++nf)
        #pragma unroll
        for (int kk=0; kk<2; ++kk)
          acc[mf][nf] = __builtin_amdgcn_mfma_f32_16x16x32_bf16(a0[mf][kk], b0[nf][kk], acc[mf][nf], 0,0,0);
    __builtin_amdgcn_s_setprio(0);
    __builtin_amdgcn_s_barrier();

    // ---- phase 2: load B(n-half1); stage issues 2,3; MFMA m0n1
    #pragma unroll
    for (int nf=0; nf<2; ++nf)
      #pragma unroll
      for (int kk=0; kk<2; ++kk)
        b1[nf][kk] = *(const short8*)(Bb + ((wn*4+2+nf)*2+kk)*1024 + ro);
    if (pf){ stage2(buf^1, k0n, 2); stage2(buf^1, k0n, 3); }
    __builtin_amdgcn_s_barrier();
    __builtin_amdgcn_s_setprio(1);
    #pragma unroll
    for (int mf=0; mf<4; ++mf)
      #pragma unroll
      for (int nf=0; nf<2; ++nf)
        #pragma unroll
        for (int kk=0; kk<2; ++kk)
          acc[mf][2+nf] = __builtin_amdgcn_mfma_f32_16x16x32_bf16(a0[mf][kk], b1[nf][kk], acc[mf][2+nf], 0,0,0);
    __builtin_amdgcn_s_setprio(0);
    __builtin_amdgcn_s_barrier();

    // ---- phase 3: load A(m-half1); MFMA m1n1
    #pragma unroll
    for (int mf=0; mf<4; ++mf)
      #pragma unroll
      for (int kk=0; kk<2; ++kk)
        a1[mf][kk] = *(const short8*)(Ab + ((wm*8+4+mf)*2+kk)*1024 + ro);
    __builtin_amdgcn_s_barrier();
    __builtin_amdgcn_s_setprio(1);
    #pragma unroll
    for (int mf=0; mf<4; ++mf)
      #pragma unroll
      for (int nf=0; nf<2; ++nf)
        #pragma unroll
        for (int kk=0; kk<2; ++kk)
          acc[4+mf][2+nf] = __builtin_amdgcn_mfma_f32_16x16x32_bf16(a1[mf][kk], b1[nf][kk], acc[4+mf][2+nf], 0,0,0);
    __builtin_amdgcn_s_setprio(0);
    __builtin_amdgcn_s_barrier();

    // ---- phase 4: no loads; wait next tile staged; MFMA m1n0
    if (pf) asm volatile("s_waitcnt vmcnt(0)" ::: "memory");
    __builtin_amdgcn_s_barrier();
    __builtin_amdgcn_s_setprio(1);
    #pragma unroll
    for (int mf=0; mf<4; ++mf)
      #pragma unroll
      for (int nf=0; nf<2; ++nf)
        #pragma unroll
        for (int kk=0; kk<2; ++kk)
          acc[4+mf][nf] = __builtin_amdgcn_mfma_f32_16x16x32_bf16(a1[mf][kk], b0[nf][kk], acc[4+mf][nf], 0,0,0);
    __builtin_amdgcn_s_setprio(0);
    __builtin_amdgcn_s_barrier();
  }

  // epilogue
  #pragma unroll
  for (int mf=0; mf<8; ++mf){
    #pragma unroll
    for (int nf=0; nf<4; ++nf){
      int col = colBase + wn*64 + nf*16 + l15;
      float bv = bias[col];
      #pragma unroll
      for (int j=0; j<4; ++j){
        int row = rowBase + wm*128 + mf*16 + quad*4 + j;
        float v = acc[mf][nf][j] + bv;
        if (RELU) v = fmaxf(v, 0.f);
        if (BF16OUT) ((u16*)Cp)[(size_t)row*N + col] = f2b(v);
        else         ((float*)Cp)[(size_t)row*N + col] = v;
      }
    }
  }
}

// ---------------- GEMM 128x128 (proven 2-phase), with concurrent split-K ----------------
template<bool RELU, bool BF16OUT, bool BIAS>
__global__ __launch_bounds__(256) void k_gemm(
    const u16* __restrict__ A, const u16* __restrict__ Bt,
    const float* __restrict__ bias, void* __restrict__ Cp,
    int M, int N, int Kc, int lda, int ldb){
  __shared__ __align__(16) char lds[32768];
  const int tid = threadIdx.x;
  const int lane = tid & 63, wid = tid >> 6;
  const int quad = lane >> 4, l15 = lane & 15;
  const int wr = wid >> 1, wc = wid & 1;
  const int nwg = gridDim.x * gridDim.y;
  int lid = blockIdx.y * gridDim.x + blockIdx.x;
  lid = (lid & 7) * (nwg >> 3) + (lid >> 3);
  const int bx = lid % gridDim.x, by = lid / gridDim.x;
  const int rowBase = by * 128, colBase = bx * 128;
  const u16* Az = A  + (size_t)blockIdx.z * Kc;
  const u16* Bz = Bt + (size_t)blockIdx.z * Kc;
  f32x4 acc[4][4] = {};
  const int srow = lane >> 3;
  const int scol = lane & 7;
  for (int k0 = 0; k0 < Kc; k0 += 64) {
    __syncthreads();
    #pragma unroll
    for (int i=0;i<4;++i){
      int wch = wid*4 + i;
      int row = wch*8 + srow;
      int c   = scol ^ (row & 7);
      const u16* ga = Az + (size_t)(rowBase+row)*lda + k0 + c*8;
      __builtin_amdgcn_global_load_lds(AS1C(ga), AS3P(lds + wch*1024), 16, 0, 0);
      const u16* gb = Bz + (size_t)(colBase+row)*ldb + k0 + c*8;
      __builtin_amdgcn_global_load_lds(AS1C(gb), AS3P(lds + 16384 + wch*1024), 16, 0, 0);
    }
    __syncthreads();
    #pragma unroll
    for (int kk=0;kk<2;++kk){
      short8 af[4], bfr[4];
      #pragma unroll
      for (int m=0;m<4;++m){
        int r = wr*64 + m*16 + l15;
        af[m] = *(const short8*)(lds + ((r*128 + kk*64 + quad*16) ^ ((r&7)<<4)));
      }
      #pragma unroll
      for (int n=0;n<4;++n){
        int r = wc*64 + n*16 + l15;
        bfr[n] = *(const short8*)(lds + 16384 + ((r*128 + kk*64 + quad*16) ^ ((r&7)<<4)));
      }
      __builtin_amdgcn_s_setprio(1);
      #pragma unroll
      for (int m=0;m<4;++m)
        #pragma unroll
        for (int n=0;n<4;++n)
          acc[m][n] = __builtin_amdgcn_mfma_f32_16x16x32_bf16(af[m], bfr[n], acc[m][n], 0,0,0);
      __builtin_amdgcn_s_setprio(0);
    }
  }
  float* Cf = (float*)Cp + (size_t)blockIdx.z * M * N;
  #pragma unroll
  for (int m=0;m<4;++m){
    #pragma unroll
    for (int n=0;n<4;++n){
      int col = colBase + wc*64 + n*16 + l15;
      float bv = (BIAS && blockIdx.z == 0) ? bias[col] : 0.f;
      #pragma unroll
      for (int j=0;j<4;++j){
        int row = rowBase + wr*64 + m*16 + quad*4 + j;
        float v = acc[m][n][j] + bv;
        if (RELU) v = fmaxf(v, 0.f);
        if (BF16OUT) ((u16*)Cp)[(size_t)row*N + col] = f2b(v);
        else         Cf[(size_t)row*N + col] = v;
      }
    }
  }
}

// ---------------- RoPE in-place on fused QKV: Q cols scaled by 1/8, K cols ----------------
__global__ void k_rope(u16* __restrict__ QKV,
                       const float* __restrict__ cosT, const float* __restrict__ sinT){
  int idx = blockIdx.x*256 + threadIdx.x;
  int row = idx >> 9, p = idx & 511;
  int s = row & (SEQ-1);
  float c = cosT[s*512 + p], sn = sinT[s*512 + p];
  u16* qp = QKV + (size_t)row*NQKV + 2*p;
  u16* kp = qp + 1024;
  ushort2 q = *(ushort2*)qp;
  ushort2 k = *(ushort2*)kp;
  float qx = b2f(q.x), qy = b2f(q.y), kx = b2f(k.x), ky = b2f(k.y);
  const float scale = 0.125f;
  ushort2 qo, ko;
  qo.x = f2b((qx*c - qy*sn)*scale);
  qo.y = f2b((qx*sn + qy*c)*scale);
  ko.x = f2b(kx*c - ky*sn);
  ko.y = f2b(kx*sn + ky*c);
  *(ushort2*)qp = qo;
  *(ushort2*)kp = ko;
}

// ---------------- flash attention: swapped QK^T, in-reg softmax, 2-phase dbuf ----------------
__global__ __launch_bounds__(256) void k_attn(
    const u16* __restrict__ QKV, const u16* __restrict__ VT, u16* __restrict__ Xo){
  const int qt = blockIdx.x, h = blockIdx.y, b = blockIdx.z;
  const int tid = threadIdx.x, lane = tid & 63, wid = tid >> 6;
  const int l31 = lane & 31, hi = lane >> 5;
  __shared__ __align__(16) char lds[32768];
  const int srow = lane >> 3, scol = lane & 7;

  short8 qf[4];
  {
    const u16* qrow = QKV + (size_t)(b*SEQ + qt*128 + wid*32 + l31)*NQKV + h*HDIM;
    #pragma unroll
    for (int dk=0; dk<4; ++dk)
      qf[dk] = *(const short8*)(qrow + dk*16 + 8*hi);
  }
  float m_run = -1e30f, s_run = 0.f;
  f32x16 oacc[2] = {};
  const size_t krow0 = (size_t)(b*SEQ);

  auto do_stage = [&](int buf, int kt){
    char* kdst = lds + buf*16384;
    char* vdst = kdst + 8192;
    #pragma unroll
    for (int i=0;i<2;++i){
      int wch = wid*2 + i;
      int row = wch*8 + srow;
      int c = scol ^ (row & 7);
      const u16* gk = QKV + (krow0 + kt*64 + row)*NQKV + 1024 + h*HDIM + c*8;
      __builtin_amdgcn_global_load_lds(AS1C(gk), AS3P(kdst + wch*1024), 16, 0, 0);
      const u16* gv = VT + (size_t)(h*HDIM + row)*NROWS + b*SEQ + kt*64 + c*8;
      __builtin_amdgcn_global_load_lds(AS1C(gv), AS3P(vdst + wch*1024), 16, 0, 0);
    }
  };

  auto do_tile = [&](int buf){
    char* kb = lds + buf*16384;
    char* vb = kb + 8192;
    f32x16 pacc[2] = {};
    __builtin_amdgcn_s_setprio(1);
    #pragma unroll
    for (int kbk=0;kbk<2;++kbk){
      #pragma unroll
      for (int dk=0;dk<4;++dk){
        int row = kbk*32 + l31;
        short8 kf = *(const short8*)(kb + ((row*128 + dk*32 + 16*hi) ^ ((row&7)<<4)));
        pacc[kbk] = __builtin_amdgcn_mfma_f32_32x32x16_bf16(kf, qf[dk], pacc[kbk], 0,0,0);
      }
    }
    __builtin_amdgcn_s_setprio(0);
    float tmax = -1e30f;
    #pragma unroll
    for (int kbk=0;kbk<2;++kbk)
      #pragma unroll
      for (int r=0;r<16;++r) tmax = fmaxf(tmax, pacc[kbk][r]);
    tmax = fmaxf(tmax, __shfl_xor(tmax, 32));
    if (__any(tmax > m_run + 8.0f)){
      float mnew = fmaxf(m_run, tmax);
      float a = __expf(m_run - mnew);
      s_run *= a;
      m_run = mnew;
      #pragma unroll
      for (int r=0;r<16;++r){
        int src = (r&3) + 8*(r>>2) + 4*hi;
        float ar = __shfl(a, src);
        oacc[0][r] *= ar;
        oacc[1][r] *= ar;
      }
    }
    float p[2][16];
    float psum = 0.f;
    #pragma unroll
    for (int kbk=0;kbk<2;++kbk)
      #pragma unroll
      for (int r=0;r<16;++r){
        float e = __expf(pacc[kbk][r] - m_run);
        p[kbk][r] = e;
        psum += e;
      }
    psum += __shfl_xor(psum, 32);
    s_run += psum;
    short8 pa[4];
    #pragma unroll
    for (int kbk=0;kbk<2;++kbk){
      #pragma unroll
      for (int s=0;s<2;++s){
        u32 X0, X1, Y0, Y1;
        asm("v_cvt_pk_bf16_f32 %0, %1, %2" : "=v"(X0) : "v"(p[kbk][8*s+0]), "v"(p[kbk][8*s+1]));
        asm("v_cvt_pk_bf16_f32 %0, %1, %2" : "=v"(X1) : "v"(p[kbk][8*s+2]), "v"(p[kbk][8*s+3]));
        asm("v_cvt_pk_bf16_f32 %0, %1, %2" : "=v"(Y0) : "v"(p[kbk][8*s+4]), "v"(p[kbk][8*s+5]));
        asm("v_cvt_pk_bf16_f32 %0, %1, %2" : "=v"(Y1) : "v"(p[kbk][8*s+6]), "v"(p[kbk][8*s+7]));
        asm volatile("v_permlane32_swap_b32 %0, %1" : "+v"(X0), "+v"(Y0));
        asm volatile("v_permlane32_swap_b32 %0, %1" : "+v"(X1), "+v"(Y1));
        union { u32 w[4]; short8 s8; } pu;
        pu.w[0] = X0; pu.w[1] = X1; pu.w[2] = Y0; pu.w[3] = Y1;
        pa[2*kbk+s] = pu.s8;
      }
    }
    __builtin_amdgcn_s_setprio(1);
    #pragma unroll
    for (int db=0;db<2;++db){
      #pragma unroll
      for (int ks=0;ks<4;++ks){
        int row = db*32 + l31;
        short8 vf = *(const short8*)(vb + ((row*128 + ks*32 + 16*hi) ^ ((row&7)<<4)));
        oacc[db] = __builtin_amdgcn_mfma_f32_32x32x16_bf16(pa[ks], vf, oacc[db], 0,0,0);
      }
    }
    __builtin_amdgcn_s_setprio(0);
  };

  do_stage(0, 0);
  __syncthreads();
  const int NT = SEQ/64;
  #pragma unroll 1
  for (int kt=0; kt<NT; kt+=2){
    do_stage(1, kt+1);
    do_tile(0);
    __syncthreads();
    if (kt+2 < NT) do_stage(0, kt+2);
    do_tile(1);
    __syncthreads();
  }
  #pragma unroll
  for (int r=0;r<16;++r){
    int crow = (r&3) + 8*(r>>2) + 4*hi;
    float sq = __shfl(s_run, crow);
    float rs = __builtin_amdgcn_rcpf(sq);
    int grow = b*SEQ + qt*128 + wid*32 + crow;
    Xo[(size_t)grow*DIM + h*HDIM + l31]      = f2b(oacc[0][r] * rs);
    Xo[(size_t)grow*DIM + h*HDIM + 32 + l31] = f2b(oacc[1][r] * rs);
  }
}

// ---------------- residual + PARTS partials + layernorm (row per block) ----------------
template<int PARTS, bool WBF>
__global__ __launch_bounds__(256) void k_ln(
    const float* __restrict__ a, const float* __restrict__ p0, const float* __restrict__ p1,
    const float* __restrict__ g, const float* __restrict__ be,
    float* __restrict__ outf, u16* __restrict__ outb){
  const int row = blockIdx.x, tid = threadIdx.x;
  __shared__ float red[8];
  float4 av = ((const float4*)(a  + (size_t)row*DIM))[tid];
  float4 b0 = ((const float4*)(p0 + (size_t)row*DIM))[tid];
  float4 b1 = ((const float4*)(p1 + (size_t)row*DIM))[tid];
  float x0 = av.x+b0.x+b1.x, x1 = av.y+b0.y+b1.y, x2 = av.z+b0.z+b1.z, x3 = av.w+b0.w+b1.w;
  float s = x0+x1+x2+x3;
  #pragma unroll
  for (int o=32;o>=1;o>>=1) s += __shfl_down(s, o);
  if ((tid&63)==0) red[tid>>6] = s;
  __syncthreads();
  float mean = (red[0]+red[1]+red[2]+red[3]) * (1.0f/DIM);
  float d0=x0-mean, d1=x1-mean, d2=x2-mean, d3=x3-mean;
  float vs = d0*d0+d1*d1+d2*d2+d3*d3;
  #pragma unroll
  for (int o=32;o>=1;o>>=1) vs += __shfl_down(vs, o);
  if ((tid&63)==0) red[4+(tid>>6)] = vs;
  __syncthreads();
  float var = (red[4]+red[5]+red[6]+red[7]) * (1.0f/DIM);
  float rs = rsqrtf(var + 1e-5f);
  float4 gv = ((const float4*)g)[tid];
  float4 bev = ((const float4*)be)[tid];
  float4 y;
  y.x = d0*rs*gv.x + bev.x;
  y.y = d1*rs*gv.y + bev.y;
  y.z = d2*rs*gv.z + bev.z;
  y.w = d3*rs*gv.w + bev.w;
  ((float4*)(outf + (size_t)row*DIM))[tid] = y;
  if (WBF){
    ushort4 o4; o4.x=f2b(y.x); o4.y=f2b(y.y); o4.z=f2b(y.z); o4.w=f2b(y.w);
    ((ushort4*)(outb + (size_t)row*DIM))[tid] = o4;
  }
}

extern "C" void kernel_launch(void* const* d_in, const int* in_sizes, int n_in,
                              void* d_out, int out_size, void* d_ws, size_t ws_size,
                              hipStream_t stream){
  (void)in_sizes; (void)n_in; (void)out_size; (void)ws_size;
  const float* src  = (const float*)d_in[0];
  const float* Wq   = (const float*)d_in[1];
  const float* bq   = (const float*)d_in[2];
  const float* Wk   = (const float*)d_in[3];
  const float* bk   = (const float*)d_in[4];
  const float* Wv   = (const float*)d_in[5];
  const float* bv   = (const float*)d_in[6];
  const float* Wo   = (const float*)d_in[7];
  const float* bo   = (const float*)d_in[8];
  const float* ln1g = (const float*)d_in[9];
  const float* ln1b = (const float*)d_in[10];
  const float* W1   = (const float*)d_in[11];
  const float* b1   = (const float*)d_in[12];
  const float* W2   = (const float*)d_in[13];
  const float* b2   = (const float*)d_in[14];
  const float* ln2g = (const float*)d_in[15];
  const float* ln2b = (const float*)d_in[16];
  const float* rc   = (const float*)d_in[17];
  const float* rsn  = (const float*)d_in[18];

  char* ws = (char*)d_ws;
  const size_t MB = (size_t)1<<20;
  u16* Xbf   = (u16*)(ws);
  u16* QKV   = (u16*)(ws + 8*MB);
  u16* VTb   = (u16*)(ws + 32*MB);
  float* aop   = (float*)(ws + 8*MB);
  float* ff2p  = (float*)(ws + 8*MB);
  u16* xat   = (u16*)(ws + 40*MB);
  u16* hbf   = (u16*)(ws + 48*MB);
  u16* WqkvT = (u16*)(ws + 56*MB);
  u16* WoT   = (u16*)(ws + 62*MB);
  u16* W1T   = (u16*)(ws + 64*MB);
  u16* W2T   = (u16*)(ws + 72*MB);
  u16* ff1   = (u16*)(ws + 80*MB);
  float* h   = (float*)(ws + 112*MB);
  float* bqkv= (float*)(ws + 128*MB);
  const size_t P16 = 16*MB/4;

  // allow 128KB dynamic LDS for the 8-phase kernels (idempotent, deterministic)
  hipFuncSetAttribute((const void*)&k_gemm256<false,true>,
                      hipFuncAttributeMaxDynamicSharedMemorySize, 131072);
  hipFuncSetAttribute((const void*)&k_gemm256<true,true>,
                      hipFuncAttributeMaxDynamicSharedMemorySize, 131072);

  dim3 blk(256);
  k_cast_bf16<<<dim3(NROWS*DIM/1024), blk, 0, stream>>>(src, Xbf, NROWS*DIM/4);
  k_transpose_cast<<<dim3(DIM/32, DIM/32), blk, 0, stream>>>(Wq, WqkvT, DIM, DIM);
  k_transpose_cast<<<dim3(DIM/32, DIM/32), blk, 0, stream>>>(Wk, WqkvT + (size_t)1024*1024, DIM, DIM);
  k_transpose_cast<<<dim3(DIM/32, DIM/32), blk, 0, stream>>>(Wv, WqkvT + (size_t)2048*1024, DIM, DIM);
  k_transpose_cast<<<dim3(DIM/32, DIM/32), blk, 0, stream>>>(Wo, WoT, DIM, DIM);
  k_transpose_cast<<<dim3(PFF/32, DIM/32), blk, 0, stream>>>(W1, W1T, DIM, PFF);
  k_transpose_cast<<<dim3(DIM/32, PFF/32), blk, 0, stream>>>(W2, W2T, PFF, DIM);
  k_pack3<<<dim3(12), blk, 0, stream>>>(bq, bk, bv, bqkv);

  // fused QKV GEMM (8-phase 256^2): [4096][1024] x [3072][1024]^T -> bf16
  k_gemm256<false,true><<<dim3(NQKV/256, NROWS/256), dim3(512), 131072, stream>>>(
      Xbf, WqkvT, bqkv, QKV, NROWS, NQKV, DIM, DIM, DIM);
  k_rope<<<dim3(NROWS*512/256), blk, 0, stream>>>(QKV, rc, rsn);
  k_transpose_v<<<dim3(DIM/32, NROWS/32), blk, 0, stream>>>(QKV, VTb);
  k_attn<<<dim3(SEQ/128, NH, BATCH), blk, 0, stream>>>(QKV, VTb, xat);
  // Wo GEMM, concurrent split-K=2 (512 blocks)
  k_gemm<false,false,true><<<dim3(DIM/128, NROWS/128, 2), blk, 0, stream>>>(
      xat, WoT, bo, aop, NROWS, DIM, 512, DIM, DIM);
  k_ln<2,true><<<dim3(NROWS), blk, 0, stream>>>(src, aop, aop + P16, ln1g, ln1b, h, hbf);
  // FF1 GEMM (8-phase 256^2) + ReLU: [4096][1024] x [4096][1024]^T -> bf16
  k_gemm256<true,true><<<dim3(PFF/256, NROWS/256), dim3(512), 131072, stream>>>(
      hbf, W1T, b1, ff1, NROWS, PFF, DIM, DIM, DIM);
  // FF2 GEMM, concurrent split-K=2 (512 blocks, Kc=2048)
  k_gemm<false,false,true><<<dim3(DIM/128, NROWS/128, 2), blk, 0, stream>>>(
      ff1, W2T, b2, ff2p, NROWS, DIM, 2048, PFF, PFF);
  k_ln<2,false><<<dim3(NROWS), blk, 0, stream>>>(h, ff2p, ff2p + P16, ln2g, ln2b, (float*)d_out, nullptr);
}

// Round 9
// 250.822 us; speedup vs baseline: 1.2929x; 1.0181x over previous
//
#include <hip/hip_runtime.h>

#define SEQ 2048
#define DIM 1024
#define NH 16
#define HDIM 64
#define PFF 4096
#define NROWS 4096  // B*S
#define BATCH 2
#define NQKV 3072

typedef unsigned short u16;
typedef unsigned int u32;
typedef __attribute__((ext_vector_type(8))) short short8;
typedef __attribute__((ext_vector_type(4))) float f32x4;
typedef __attribute__((ext_vector_type(16))) float f32x16;

__device__ inline float b2f(u16 u){ return __uint_as_float(((u32)u)<<16); }
__device__ inline u16 f2b(float f){
  u32 u = __float_as_uint(f);
  u32 r = u + 0x7FFFu + ((u>>16)&1u);
  return (u16)(r>>16);
}
__device__ __forceinline__ float fexp2(float x){      // v_exp_f32 = 2^x
  float r; asm("v_exp_f32 %0, %1" : "=v"(r) : "v"(x)); return r;
}
__device__ __forceinline__ float fmax3(float a, float b, float c){
  float r; asm("v_max3_f32 %0, %1, %2, %3" : "=v"(r) : "v"(a), "v"(b), "v"(c)); return r;
}

// C-style casts: clang allows addrspacecast via C-style cast (static_cast does not)
#define AS1C(p) ((const __attribute__((address_space(1))) unsigned int*)(p))
#define AS3P(p) ((__attribute__((address_space(3))) unsigned int*)(p))

// ---------------- elementwise cast fp32 -> bf16 (float4 per thread) ----------------
__global__ void k_cast_bf16(const float* __restrict__ in, u16* __restrict__ out, int n4){
  int i = blockIdx.x*256 + threadIdx.x;
  if (i >= n4) return;
  float4 v = ((const float4*)in)[i];
  ushort4 o;
  o.x = f2b(v.x); o.y = f2b(v.y); o.z = f2b(v.z); o.w = f2b(v.w);
  ((ushort4*)out)[i] = o;
}

// ---------------- transpose + cast: in fp32 [R][C] -> out bf16 [C][R] ----------------
__global__ __launch_bounds__(256) void k_transpose_cast(const float* __restrict__ in,
                                                        u16* __restrict__ out, int R, int C){
  __shared__ float tile[32][33];
  int tx = threadIdx.x & 31, ty = threadIdx.x >> 5;
  int c0 = blockIdx.x*32, r0 = blockIdx.y*32;
  #pragma unroll
  for (int i=0;i<4;++i)
    tile[ty+i*8][tx] = in[(size_t)(r0+ty+i*8)*C + c0 + tx];
  __syncthreads();
  #pragma unroll
  for (int i=0;i<4;++i)
    out[(size_t)(c0+ty+i*8)*R + r0 + tx] = f2b(tile[tx][ty+i*8]);
}

// ---------------- bf16 transpose: VT[d][r] = QKV[r][2048+d] ----------------
__global__ __launch_bounds__(256) void k_transpose_v(const u16* __restrict__ QKV, u16* __restrict__ VT){
  __shared__ u16 tile[32][34];
  int tx = threadIdx.x & 31, ty = threadIdx.x >> 5;
  int d0 = blockIdx.x*32, r0 = blockIdx.y*32;
  #pragma unroll
  for (int i=0;i<4;++i)
    tile[ty+i*8][tx] = QKV[(size_t)(r0+ty+i*8)*NQKV + 2048 + d0 + tx];
  __syncthreads();
  #pragma unroll
  for (int i=0;i<4;++i)
    VT[(size_t)(d0+ty+i*8)*NROWS + r0 + tx] = tile[tx][ty+i*8];
}

// ---------------- pack 3 bias vectors ----------------
__global__ void k_pack3(const float* __restrict__ a, const float* __restrict__ b,
                        const float* __restrict__ c, float* __restrict__ o){
  int i = blockIdx.x*256 + threadIdx.x;
  if (i >= NQKV) return;
  o[i] = i < 1024 ? a[i] : (i < 2048 ? b[i-1024] : c[i-2048]);
}

// ================= 8-phase 256x256 GEMM (T2+T3+T4+T5 stack, m201-style) =================
// 512 threads = 8 waves (2M x 4N). BK=64. LDS = 2 bufs x (A 32KB + B 32KB) = 128KB dynamic.
// Subtiled LDS [16 rows][32 k] per 1024B; linear gload_lds dest; conflict-free frag reads.
// SPLIT>1: concurrent split-K over gridDim.z, bf16 partials at Cp + z*M*N, bias on z==0.
template<bool RELU, bool BF16OUT, int SPLIT>
__global__ __launch_bounds__(512, 2) void k_gemm256(
    const u16* __restrict__ A, const u16* __restrict__ Bt,
    const float* __restrict__ bias, void* __restrict__ Cp,
    int M, int N, int Kc, int lda, int ldb){
  extern __shared__ char lds[];
  const int tid = threadIdx.x;
  const int lane = tid & 63, wid = tid >> 6;
  const int quad = lane >> 4, l15 = lane & 15;
  const int wm = wid >> 2, wn = wid & 3;
  const int ro = (l15*4 + quad)*16;        // in-subtile frag offset
  const int srow = lane >> 2;              // staging: row within subtile
  const int sk   = (lane & 3)*8;           // staging: k within subtile
  const int nwg = gridDim.x * gridDim.y;
  int lid = blockIdx.y * gridDim.x + blockIdx.x;
  lid = (lid & 7) * (nwg >> 3) + (lid >> 3);
  const int bx = lid % gridDim.x, by = lid / gridDim.x;
  const int rowBase = by*256, colBase = bx*256;
  const u16* Az = A  + (size_t)blockIdx.z * Kc;
  const u16* Bz = Bt + (size_t)blockIdx.z * Kc;

  f32x4 acc[8][4] = {};

  auto stage2 = [&](int buf, int k0, int i){
    int idx = i*8 + wid;                       // 0..31
    int rs = idx >> 1, ks = idx & 1;
    const u16* ga = Az + (size_t)(rowBase + rs*16 + srow)*lda + k0 + ks*32 + sk;
    __builtin_amdgcn_global_load_lds(AS1C(ga), AS3P(lds + buf*65536 + idx*1024), 16, 0, 0);
    const u16* gb = Bz + (size_t)(colBase + rs*16 + srow)*ldb + k0 + ks*32 + sk;
    __builtin_amdgcn_global_load_lds(AS1C(gb), AS3P(lds + buf*65536 + 32768 + idx*1024), 16, 0, 0);
  };

  #pragma unroll
  for (int i=0;i<4;++i) stage2(0, 0, i);
  __syncthreads();

  const int NT = Kc >> 6;
  #pragma unroll 1
  for (int t=0; t<NT; ++t){
    const int buf = t & 1;
    const bool pf = (t+1 < NT);
    const int k0n = (t+1)*64;
    char* Ab = lds + buf*65536;
    char* Bb = Ab + 32768;
    short8 a0[4][2], a1[4][2], b0[2][2], b1[2][2];

    // ---- phase 1
    #pragma unroll
    for (int mf=0; mf<4; ++mf)
      #pragma unroll
      for (int kk=0; kk<2; ++kk)
        a0[mf][kk] = *(const short8*)(Ab + ((wm*8+mf)*2+kk)*1024 + ro);
    #pragma unroll
    for (int nf=0; nf<2; ++nf)
      #pragma unroll
      for (int kk=0; kk<2; ++kk)
        b0[nf][kk] = *(const short8*)(Bb + ((wn*4+nf)*2+kk)*1024 + ro);
    if (pf){ stage2(buf^1, k0n, 0); stage2(buf^1, k0n, 1); }
    __builtin_amdgcn_s_barrier();
    __builtin_amdgcn_s_setprio(1);
    #pragma unroll
    for (int mf=0; mf<4; ++mf)
      #pragma unroll
      for (int nf=0; nf<2; ++nf)
        #pragma unroll
        for (int kk=0; kk<2; ++kk)
          acc[mf][nf] = __builtin_amdgcn_mfma_f32_16x16x32_bf16(a0[mf][kk], b0[nf][kk], acc[mf][nf], 0,0,0);
    __builtin_amdgcn_s_setprio(0);
    __builtin_amdgcn_s_barrier();

    // ---- phase 2
    #pragma unroll
    for (int nf=0; nf<2; ++nf)
      #pragma unroll
      for (int kk=0; kk<2; ++kk)
        b1[nf][kk] = *(const short8*)(Bb + ((wn*4+2+nf)*2+kk)*1024 + ro);
    if (pf){ stage2(buf^1, k0n, 2); stage2(buf^1, k0n, 3); }
    __builtin_amdgcn_s_barrier();
    __builtin_amdgcn_s_setprio(1);
    #pragma unroll
    for (int mf=0; mf<4; ++mf)
      #pragma unroll
      for (int nf=0; nf<2; ++nf)
        #pragma unroll
        for (int kk=0; kk<2; ++kk)
          acc[mf][2+nf] = __builtin_amdgcn_mfma_f32_16x16x32_bf16(a0[mf][kk], b1[nf][kk], acc[mf][2+nf], 0,0,0);
    __builtin_amdgcn_s_setprio(0);
    __builtin_amdgcn_s_barrier();

    // ---- phase 3
    #pragma unroll
    for (int mf=0; mf<4; ++mf)
      #pragma unroll
      for (int kk=0; kk<2; ++kk)
        a1[mf][kk] = *(const short8*)(Ab + ((wm*8+4+mf)*2+kk)*1024 + ro);
    __builtin_amdgcn_s_barrier();
    __builtin_amdgcn_s_setprio(1);
    #pragma unroll
    for (int mf=0; mf<4; ++mf)
      #pragma unroll
      for (int nf=0; nf<2; ++nf)
        #pragma unroll
        for (int kk=0; kk<2; ++kk)
          acc[4+mf][2+nf] = __builtin_amdgcn_mfma_f32_16x16x32_bf16(a1[mf][kk], b1[nf][kk], acc[4+mf][2+nf], 0,0,0);
    __builtin_amdgcn_s_setprio(0);
    __builtin_amdgcn_s_barrier();

    // ---- phase 4
    if (pf) asm volatile("s_waitcnt vmcnt(0)" ::: "memory");
    __builtin_amdgcn_s_barrier();
    __builtin_amdgcn_s_setprio(1);
    #pragma unroll
    for (int mf=0; mf<4; ++mf)
      #pragma unroll
      for (int nf=0; nf<2; ++nf)
        #pragma unroll
        for (int kk=0; kk<2; ++kk)
          acc[4+mf][nf] = __builtin_amdgcn_mfma_f32_16x16x32_bf16(a1[mf][kk], b0[nf][kk], acc[4+mf][nf], 0,0,0);
    __builtin_amdgcn_s_setprio(0);
    __builtin_amdgcn_s_barrier();
  }

  u16* Cb = (u16*)Cp + (SPLIT > 1 ? (size_t)blockIdx.z * M * N : 0);
  float* Cf = (float*)Cp + (SPLIT > 1 ? (size_t)blockIdx.z * M * N : 0);
  #pragma unroll
  for (int mf=0; mf<8; ++mf){
    #pragma unroll
    for (int nf=0; nf<4; ++nf){
      int col = colBase + wn*64 + nf*16 + l15;
      float bv = (SPLIT == 1 || blockIdx.z == 0) ? bias[col] : 0.f;
      #pragma unroll
      for (int j=0; j<4; ++j){
        int row = rowBase + wm*128 + mf*16 + quad*4 + j;
        float v = acc[mf][nf][j] + bv;
        if (RELU) v = fmaxf(v, 0.f);
        if (BF16OUT) Cb[(size_t)row*N + col] = f2b(v);
        else         Cf[(size_t)row*N + col] = v;
      }
    }
  }
}

// ---------------- GEMM 128x128 (proven 2-phase), with concurrent split-K ----------------
template<bool RELU, bool BF16OUT, bool BIAS>
__global__ __launch_bounds__(256) void k_gemm(
    const u16* __restrict__ A, const u16* __restrict__ Bt,
    const float* __restrict__ bias, void* __restrict__ Cp,
    int M, int N, int Kc, int lda, int ldb){
  __shared__ __align__(16) char lds[32768];
  const int tid = threadIdx.x;
  const int lane = tid & 63, wid = tid >> 6;
  const int quad = lane >> 4, l15 = lane & 15;
  const int wr = wid >> 1, wc = wid & 1;
  const int nwg = gridDim.x * gridDim.y;
  int lid = blockIdx.y * gridDim.x + blockIdx.x;
  lid = (lid & 7) * (nwg >> 3) + (lid >> 3);
  const int bx = lid % gridDim.x, by = lid / gridDim.x;
  const int rowBase = by * 128, colBase = bx * 128;
  const u16* Az = A  + (size_t)blockIdx.z * Kc;
  const u16* Bz = Bt + (size_t)blockIdx.z * Kc;
  f32x4 acc[4][4] = {};
  const int srow = lane >> 3;
  const int scol = lane & 7;
  for (int k0 = 0; k0 < Kc; k0 += 64) {
    __syncthreads();
    #pragma unroll
    for (int i=0;i<4;++i){
      int wch = wid*4 + i;
      int row = wch*8 + srow;
      int c   = scol ^ (row & 7);
      const u16* ga = Az + (size_t)(rowBase+row)*lda + k0 + c*8;
      __builtin_amdgcn_global_load_lds(AS1C(ga), AS3P(lds + wch*1024), 16, 0, 0);
      const u16* gb = Bz + (size_t)(colBase+row)*ldb + k0 + c*8;
      __builtin_amdgcn_global_load_lds(AS1C(gb), AS3P(lds + 16384 + wch*1024), 16, 0, 0);
    }
    __syncthreads();
    #pragma unroll
    for (int kk=0;kk<2;++kk){
      short8 af[4], bfr[4];
      #pragma unroll
      for (int m=0;m<4;++m){
        int r = wr*64 + m*16 + l15;
        af[m] = *(const short8*)(lds + ((r*128 + kk*64 + quad*16) ^ ((r&7)<<4)));
      }
      #pragma unroll
      for (int n=0;n<4;++n){
        int r = wc*64 + n*16 + l15;
        bfr[n] = *(const short8*)(lds + 16384 + ((r*128 + kk*64 + quad*16) ^ ((r&7)<<4)));
      }
      __builtin_amdgcn_s_setprio(1);
      #pragma unroll
      for (int m=0;m<4;++m)
        #pragma unroll
        for (int n=0;n<4;++n)
          acc[m][n] = __builtin_amdgcn_mfma_f32_16x16x32_bf16(af[m], bfr[n], acc[m][n], 0,0,0);
      __builtin_amdgcn_s_setprio(0);
    }
  }
  float* Cf = (float*)Cp + (size_t)blockIdx.z * M * N;
  #pragma unroll
  for (int m=0;m<4;++m){
    #pragma unroll
    for (int n=0;n<4;++n){
      int col = colBase + wc*64 + n*16 + l15;
      float bv = (BIAS && blockIdx.z == 0) ? bias[col] : 0.f;
      #pragma unroll
      for (int j=0;j<4;++j){
        int row = rowBase + wr*64 + m*16 + quad*4 + j;
        float v = acc[m][n][j] + bv;
        if (RELU) v = fmaxf(v, 0.f);
        if (BF16OUT) ((u16*)Cp)[(size_t)row*N + col] = f2b(v);
        else         Cf[(size_t)row*N + col] = v;
      }
    }
  }
}

// ---------------- RoPE in-place on fused QKV: Q scaled by log2e/sqrt(HD), K raw ----------------
__global__ void k_rope(u16* __restrict__ QKV,
                       const float* __restrict__ cosT, const float* __restrict__ sinT){
  int idx = blockIdx.x*256 + threadIdx.x;
  int row = idx >> 9, p = idx & 511;
  int s = row & (SEQ-1);
  float c = cosT[s*512 + p], sn = sinT[s*512 + p];
  u16* qp = QKV + (size_t)row*NQKV + 2*p;
  u16* kp = qp + 1024;
  ushort2 q = *(ushort2*)qp;
  ushort2 k = *(ushort2*)kp;
  float qx = b2f(q.x), qy = b2f(q.y), kx = b2f(k.x), ky = b2f(k.y);
  const float scale = 0.125f * 1.44269504f;   // 1/sqrt(HD) * log2(e)  (exp2-domain softmax)
  ushort2 qo, ko;
  qo.x = f2b((qx*c - qy*sn)*scale);
  qo.y = f2b((qx*sn + qy*c)*scale);
  ko.x = f2b(kx*c - ky*sn);
  ko.y = f2b(kx*sn + ky*c);
  *(ushort2*)qp = qo;
  *(ushort2*)kp = ko;
}

// ---------------- flash attention: swapped QK^T, in-reg exp2 softmax, 2-phase dbuf ----------------
__global__ __launch_bounds__(256) void k_attn(
    const u16* __restrict__ QKV, const u16* __restrict__ VT, u16* __restrict__ Xo){
  const int qt = blockIdx.x, h = blockIdx.y, b = blockIdx.z;
  const int tid = threadIdx.x, lane = tid & 63, wid = tid >> 6;
  const int l31 = lane & 31, hi = lane >> 5;
  __shared__ __align__(16) char lds[32768];
  const int srow = lane >> 3, scol = lane & 7;

  short8 qf[4];
  {
    const u16* qrow = QKV + (size_t)(b*SEQ + qt*128 + wid*32 + l31)*NQKV + h*HDIM;
    #pragma unroll
    for (int dk=0; dk<4; ++dk)
      qf[dk] = *(const short8*)(qrow + dk*16 + 8*hi);
  }
  float m_run = -1e30f, s_run = 0.f;
  f32x16 oacc[2] = {};
  const size_t krow0 = (size_t)(b*SEQ);

  auto do_stage = [&](int buf, int kt){
    char* kdst = lds + buf*16384;
    char* vdst = kdst + 8192;
    #pragma unroll
    for (int i=0;i<2;++i){
      int wch = wid*2 + i;
      int row = wch*8 + srow;
      int c = scol ^ (row & 7);
      const u16* gk = QKV + (krow0 + kt*64 + row)*NQKV + 1024 + h*HDIM + c*8;
      __builtin_amdgcn_global_load_lds(AS1C(gk), AS3P(kdst + wch*1024), 16, 0, 0);
      const u16* gv = VT + (size_t)(h*HDIM + row)*NROWS + b*SEQ + kt*64 + c*8;
      __builtin_amdgcn_global_load_lds(AS1C(gv), AS3P(vdst + wch*1024), 16, 0, 0);
    }
  };

  auto do_tile = [&](int buf){
    char* kb = lds + buf*16384;
    char* vb = kb + 8192;
    f32x16 pacc[2] = {};
    __builtin_amdgcn_s_setprio(1);
    #pragma unroll
    for (int kbk=0;kbk<2;++kbk){
      #pragma unroll
      for (int dk=0;dk<4;++dk){
        int row = kbk*32 + l31;
        short8 kf = *(const short8*)(kb + ((row*128 + dk*32 + 16*hi) ^ ((row&7)<<4)));
        pacc[kbk] = __builtin_amdgcn_mfma_f32_32x32x16_bf16(kf, qf[dk], pacc[kbk], 0,0,0);
      }
    }
    __builtin_amdgcn_s_setprio(0);
    // tile max via v_max3 chains (T17)
    float tmax = fmaxf(pacc[0][0], pacc[0][1]);
    #pragma unroll
    for (int r=2;r<16;r+=2) tmax = fmax3(tmax, pacc[0][r], pacc[0][r+1]);
    #pragma unroll
    for (int r=0;r<16;r+=2) tmax = fmax3(tmax, pacc[1][r], pacc[1][r+1]);
    tmax = fmaxf(tmax, __shfl_xor(tmax, 32));
    // defer-max (T13), log2 domain
    if (__any(tmax > m_run + 8.0f)){
      float mnew = fmaxf(m_run, tmax);
      float a = fexp2(m_run - mnew);
      s_run *= a;
      m_run = mnew;
      #pragma unroll
      for (int r=0;r<16;++r){
        int src = (r&3) + 8*(r>>2) + 4*hi;
        float ar = __shfl(a, src);
        oacc[0][r] *= ar;
        oacc[1][r] *= ar;
      }
    }
    // P = 2^(S - m_run), row-sum
    float p[2][16];
    float psum = 0.f;
    #pragma unroll
    for (int kbk=0;kbk<2;++kbk)
      #pragma unroll
      for (int r=0;r<16;++r){
        float e = fexp2(pacc[kbk][r] - m_run);
        p[kbk][r] = e;
        psum += e;
      }
    psum += __shfl_xor(psum, 32);
    s_run += psum;
    short8 pa[4];
    #pragma unroll
    for (int kbk=0;kbk<2;++kbk){
      #pragma unroll
      for (int s=0;s<2;++s){
        u32 X0, X1, Y0, Y1;
        asm("v_cvt_pk_bf16_f32 %0, %1, %2" : "=v"(X0) : "v"(p[kbk][8*s+0]), "v"(p[kbk][8*s+1]));
        asm("v_cvt_pk_bf16_f32 %0, %1, %2" : "=v"(X1) : "v"(p[kbk][8*s+2]), "v"(p[kbk][8*s+3]));
        asm("v_cvt_pk_bf16_f32 %0, %1, %2" : "=v"(Y0) : "v"(p[kbk][8*s+4]), "v"(p[kbk][8*s+5]));
        asm("v_cvt_pk_bf16_f32 %0, %1, %2" : "=v"(Y1) : "v"(p[kbk][8*s+6]), "v"(p[kbk][8*s+7]));
        asm volatile("v_permlane32_swap_b32 %0, %1" : "+v"(X0), "+v"(Y0));
        asm volatile("v_permlane32_swap_b32 %0, %1" : "+v"(X1), "+v"(Y1));
        union { u32 w[4]; short8 s8; } pu;
        pu.w[0] = X0; pu.w[1] = X1; pu.w[2] = Y0; pu.w[3] = Y1;
        pa[2*kbk+s] = pu.s8;
      }
    }
    __builtin_amdgcn_s_setprio(1);
    #pragma unroll
    for (int db=0;db<2;++db){
      #pragma unroll
      for (int ks=0;ks<4;++ks){
        int row = db*32 + l31;
        short8 vf = *(const short8*)(vb + ((row*128 + ks*32 + 16*hi) ^ ((row&7)<<4)));
        oacc[db] = __builtin_amdgcn_mfma_f32_32x32x16_bf16(pa[ks], vf, oacc[db], 0,0,0);
      }
    }
    __builtin_amdgcn_s_setprio(0);
  };

  do_stage(0, 0);
  __syncthreads();
  const int NT = SEQ/64;
  #pragma unroll 1
  for (int kt=0; kt<NT; kt+=2){
    do_stage(1, kt+1);
    do_tile(0);
    __syncthreads();
    if (kt+2 < NT) do_stage(0, kt+2);
    do_tile(1);
    __syncthreads();
  }
  #pragma unroll
  for (int r=0;r<16;++r){
    int crow = (r&3) + 8*(r>>2) + 4*hi;
    float sq = __shfl(s_run, crow);
    float rs = __builtin_amdgcn_rcpf(sq);
    int grow = b*SEQ + qt*128 + wid*32 + crow;
    Xo[(size_t)grow*DIM + h*HDIM + l31]      = f2b(oacc[0][r] * rs);
    Xo[(size_t)grow*DIM + h*HDIM + 32 + l31] = f2b(oacc[1][r] * rs);
  }
}

// ---------------- residual + 2 fp32 partials + layernorm ----------------
template<int PARTS, bool WBF>
__global__ __launch_bounds__(256) void k_ln(
    const float* __restrict__ a, const float* __restrict__ p0, const float* __restrict__ p1,
    const float* __restrict__ g, const float* __restrict__ be,
    float* __restrict__ outf, u16* __restrict__ outb){
  const int row = blockIdx.x, tid = threadIdx.x;
  __shared__ float red[8];
  float4 av = ((const float4*)(a  + (size_t)row*DIM))[tid];
  float4 b0 = ((const float4*)(p0 + (size_t)row*DIM))[tid];
  float4 b1 = ((const float4*)(p1 + (size_t)row*DIM))[tid];
  float x0 = av.x+b0.x+b1.x, x1 = av.y+b0.y+b1.y, x2 = av.z+b0.z+b1.z, x3 = av.w+b0.w+b1.w;
  float s = x0+x1+x2+x3;
  #pragma unroll
  for (int o=32;o>=1;o>>=1) s += __shfl_down(s, o);
  if ((tid&63)==0) red[tid>>6] = s;
  __syncthreads();
  float mean = (red[0]+red[1]+red[2]+red[3]) * (1.0f/DIM);
  float d0=x0-mean, d1=x1-mean, d2=x2-mean, d3=x3-mean;
  float vs = d0*d0+d1*d1+d2*d2+d3*d3;
  #pragma unroll
  for (int o=32;o>=1;o>>=1) vs += __shfl_down(vs, o);
  if ((tid&63)==0) red[4+(tid>>6)] = vs;
  __syncthreads();
  float var = (red[4]+red[5]+red[6]+red[7]) * (1.0f/DIM);
  float rs = rsqrtf(var + 1e-5f);
  float4 gv = ((const float4*)g)[tid];
  float4 bev = ((const float4*)be)[tid];
  float4 y;
  y.x = d0*rs*gv.x + bev.x;
  y.y = d1*rs*gv.y + bev.y;
  y.z = d2*rs*gv.z + bev.z;
  y.w = d3*rs*gv.w + bev.w;
  ((float4*)(outf + (size_t)row*DIM))[tid] = y;
  if (WBF){
    ushort4 o4; o4.x=f2b(y.x); o4.y=f2b(y.y); o4.z=f2b(y.z); o4.w=f2b(y.w);
    ((ushort4*)(outb + (size_t)row*DIM))[tid] = o4;
  }
}

// ---------------- residual + PARTS bf16 partials + layernorm ----------------
template<int PARTS>
__global__ __launch_bounds__(256) void k_lnp(
    const float* __restrict__ a, const u16* __restrict__ p,
    const float* __restrict__ g, const float* __restrict__ be,
    float* __restrict__ outf){
  const int row = blockIdx.x, tid = threadIdx.x;
  __shared__ float red[8];
  float4 av = ((const float4*)(a + (size_t)row*DIM))[tid];
  float x0 = av.x, x1 = av.y, x2 = av.z, x3 = av.w;
  #pragma unroll
  for (int z=0; z<PARTS; ++z){
    ushort4 pv = ((const ushort4*)(p + (size_t)z*NROWS*DIM + (size_t)row*DIM))[tid];
    x0 += b2f(pv.x); x1 += b2f(pv.y); x2 += b2f(pv.z); x3 += b2f(pv.w);
  }
  float s = x0+x1+x2+x3;
  #pragma unroll
  for (int o=32;o>=1;o>>=1) s += __shfl_down(s, o);
  if ((tid&63)==0) red[tid>>6] = s;
  __syncthreads();
  float mean = (red[0]+red[1]+red[2]+red[3]) * (1.0f/DIM);
  float d0=x0-mean, d1=x1-mean, d2=x2-mean, d3=x3-mean;
  float vs = d0*d0+d1*d1+d2*d2+d3*d3;
  #pragma unroll
  for (int o=32;o>=1;o>>=1) vs += __shfl_down(vs, o);
  if ((tid&63)==0) red[4+(tid>>6)] = vs;
  __syncthreads();
  float var = (red[4]+red[5]+red[6]+red[7]) * (1.0f/DIM);
  float rs = rsqrtf(var + 1e-5f);
  float4 gv = ((const float4*)g)[tid];
  float4 bev = ((const float4*)be)[tid];
  float4 y;
  y.x = d0*rs*gv.x + bev.x;
  y.y = d1*rs*gv.y + bev.y;
  y.z = d2*rs*gv.z + bev.z;
  y.w = d3*rs*gv.w + bev.w;
  ((float4*)(outf + (size_t)row*DIM))[tid] = y;
}

extern "C" void kernel_launch(void* const* d_in, const int* in_sizes, int n_in,
                              void* d_out, int out_size, void* d_ws, size_t ws_size,
                              hipStream_t stream){
  (void)in_sizes; (void)n_in; (void)out_size; (void)ws_size;
  const float* src  = (const float*)d_in[0];
  const float* Wq   = (const float*)d_in[1];
  const float* bq   = (const float*)d_in[2];
  const float* Wk   = (const float*)d_in[3];
  const float* bk   = (const float*)d_in[4];
  const float* Wv   = (const float*)d_in[5];
  const float* bv   = (const float*)d_in[6];
  const float* Wo   = (const float*)d_in[7];
  const float* bo   = (const float*)d_in[8];
  const float* ln1g = (const float*)d_in[9];
  const float* ln1b = (const float*)d_in[10];
  const float* W1   = (const float*)d_in[11];
  const float* b1   = (const float*)d_in[12];
  const float* W2   = (const float*)d_in[13];
  const float* b2   = (const float*)d_in[14];
  const float* ln2g = (const float*)d_in[15];
  const float* ln2b = (const float*)d_in[16];
  const float* rc   = (const float*)d_in[17];
  const float* rsn  = (const float*)d_in[18];

  char* ws = (char*)d_ws;
  const size_t MB = (size_t)1<<20;
  u16* Xbf   = (u16*)(ws);
  u16* QKV   = (u16*)(ws + 8*MB);
  u16* VTb   = (u16*)(ws + 32*MB);
  float* aop   = (float*)(ws + 8*MB);   // Wo fp32 partials: z at +z*16MB
  u16* ff2b  = (u16*)(ws + 8*MB);       // FF2 bf16 partials: z at +z*8MB (4x)
  u16* xat   = (u16*)(ws + 40*MB);
  u16* hbf   = (u16*)(ws + 48*MB);
  u16* WqkvT = (u16*)(ws + 56*MB);
  u16* WoT   = (u16*)(ws + 62*MB);
  u16* W1T   = (u16*)(ws + 64*MB);
  u16* W2T   = (u16*)(ws + 72*MB);
  u16* ff1   = (u16*)(ws + 80*MB);
  float* h   = (float*)(ws + 112*MB);
  float* bqkv= (float*)(ws + 128*MB);
  const size_t P16 = 16*MB/4;

  hipFuncSetAttribute((const void*)&k_gemm256<false,true,1>,
                      hipFuncAttributeMaxDynamicSharedMemorySize, 131072);
  hipFuncSetAttribute((const void*)&k_gemm256<true,true,1>,
                      hipFuncAttributeMaxDynamicSharedMemorySize, 131072);
  hipFuncSetAttribute((const void*)&k_gemm256<false,true,4>,
                      hipFuncAttributeMaxDynamicSharedMemorySize, 131072);

  dim3 blk(256);
  k_cast_bf16<<<dim3(NROWS*DIM/1024), blk, 0, stream>>>(src, Xbf, NROWS*DIM/4);
  k_transpose_cast<<<dim3(DIM/32, DIM/32), blk, 0, stream>>>(Wq, WqkvT, DIM, DIM);
  k_transpose_cast<<<dim3(DIM/32, DIM/32), blk, 0, stream>>>(Wk, WqkvT + (size_t)1024*1024, DIM, DIM);
  k_transpose_cast<<<dim3(DIM/32, DIM/32), blk, 0, stream>>>(Wv, WqkvT + (size_t)2048*1024, DIM, DIM);
  k_transpose_cast<<<dim3(DIM/32, DIM/32), blk, 0, stream>>>(Wo, WoT, DIM, DIM);
  k_transpose_cast<<<dim3(PFF/32, DIM/32), blk, 0, stream>>>(W1, W1T, DIM, PFF);
  k_transpose_cast<<<dim3(DIM/32, PFF/32), blk, 0, stream>>>(W2, W2T, PFF, DIM);
  k_pack3<<<dim3(12), blk, 0, stream>>>(bq, bk, bv, bqkv);

  // fused QKV GEMM (8-phase 256^2)
  k_gemm256<false,true,1><<<dim3(NQKV/256, NROWS/256), dim3(512), 131072, stream>>>(
      Xbf, WqkvT, bqkv, QKV, NROWS, NQKV, DIM, DIM, DIM);
  k_rope<<<dim3(NROWS*512/256), blk, 0, stream>>>(QKV, rc, rsn);
  k_transpose_v<<<dim3(DIM/32, NROWS/32), blk, 0, stream>>>(QKV, VTb);
  k_attn<<<dim3(SEQ/128, NH, BATCH), blk, 0, stream>>>(QKV, VTb, xat);
  // Wo GEMM, concurrent split-K=2 (512 blocks, 128^2)
  k_gemm<false,false,true><<<dim3(DIM/128, NROWS/128, 2), blk, 0, stream>>>(
      xat, WoT, bo, aop, NROWS, DIM, 512, DIM, DIM);
  k_ln<2,true><<<dim3(NROWS), blk, 0, stream>>>(src, aop, aop + P16, ln1g, ln1b, h, hbf);
  // FF1 GEMM (8-phase 256^2) + ReLU
  k_gemm256<true,true,1><<<dim3(PFF/256, NROWS/256), dim3(512), 131072, stream>>>(
      hbf, W1T, b1, ff1, NROWS, PFF, DIM, DIM, DIM);
  // FF2 GEMM (8-phase 256^2), concurrent split-K=4, bf16 partials (256 blocks = 1/CU)
  k_gemm256<false,true,4><<<dim3(DIM/256, NROWS/256, 4), dim3(512), 131072, stream>>>(
      ff1, W2T, b2, ff2b, NROWS, DIM, 1024, PFF, PFF);
  k_lnp<4><<<dim3(NROWS), blk, 0, stream>>>(h, ff2b, ln2g, ln2b, (float*)d_out);
}